// Round 13
// baseline (206.978 us; speedup 1.0000x reference)
//
#include <hip/hip_runtime.h>
#include <math.h>

#define N_TOT   4096
#define N_SRC   2048
#define DIMF    256
#define NCLASS  31
#define LAMBDA  0.01f

// median target ranks among the 2,096,128 strict-lower-triangle values.
#define K_TRI1  1048063LL
#define K_TRI2  1048064LL

// ---- ws layout (bytes) ----
#define WS_ACC    0           // 2 doubles
#define WS_HIST0  64          // 4096 u32
#define WS_HISTA  16448       // 4096 u32
#define WS_HISTB  32832       // 4096 u32
#define WS_H2A    49216       // 256 u32
#define WS_H2B    50240       // 256 u32
#define WS_STATE  51264       // 64 u32 (st[0..7])
#define WS_TICK   51520       // 4 u32 (solver final ticket)
#define WS_META   52288       // 128 i32: ncls[32], m0c[32], cstart[32], blkoff[32]
#define WS_SCAL   52800       // 16 f32: [0]=sigma, [1]=gamma0, [2]=gamma1
#define ZERO_BYTES 53248
#define WS_PERM   53248       // 4096 i32
#define WS_XN     69632       // 4096 f32
#define WS_DS     1048576     // 2048*2048 f32 (lower triangle used)
#define WS_KBLK   17825792    // class K blocks (8 MB); raw d from distbuild, exp'd in-place by solver

#define MAXW 224
#define MAXM 112
#define WPAD 116   // u16 row stride = 58 dwords: rows 8B-aligned (b64 reads);
                   // column reads: 64 lanes x 2B = 128B = 32 banks, 2 lanes/bank (free, m136)

#define DIST_BLKS 528
#define BUILD_TPC 105   // tiles per class: T<=14 -> T(T+1)/2 <= 105

__device__ __forceinline__ float bf2f(unsigned short h) {
  return __uint_as_float(((unsigned)h) << 16);
}

// f32 butterfly reduce across one wave (all lanes get the sum)
__device__ __forceinline__ float wredF(float v) {
#pragma unroll
  for (int o = 1; o < 64; o <<= 1) v += __shfl_xor(v, o, 64);
  return v;
}

// ---------------- reductions (256 threads) ----------------
__device__ __forceinline__ double blockReduceSum(double v, double* red) {
#pragma unroll
  for (int o = 32; o > 0; o >>= 1) v += __shfl_down(v, o, 64);
  int w = threadIdx.x >> 6, lane = threadIdx.x & 63;
  __syncthreads();
  if (lane == 0) red[w] = v;
  __syncthreads();
  return red[0] + red[1] + red[2] + red[3];
}

__device__ __forceinline__ void blockReduceSumMax(double s, double mx, double* red,
                                                  double& os, double& om) {
#pragma unroll
  for (int o = 32; o > 0; o >>= 1) {
    s += __shfl_down(s, o, 64);
    double u = __shfl_down(mx, o, 64);
    mx = fmax(mx, u);
  }
  int w = threadIdx.x >> 6, lane = threadIdx.x & 63;
  __syncthreads();
  if (lane == 0) { red[w] = s; red[4 + w] = mx; }
  __syncthreads();
  os = red[0] + red[1] + red[2] + red[3];
  om = fmax(fmax(red[4], red[5]), fmax(red[6], red[7]));
}

// scan over histogram (256 threads) — parallel Hillis-Steele prefix scan (measured-best)
__device__ void scan_find(const unsigned* hist, int nbins, long long k, unsigned* shOut, int tid) {
  __shared__ long long tsum[256];
  int per = nbins / 256;
  long long s = 0;
  for (int q = 0; q < per; q++) s += hist[tid * per + q];
  tsum[tid] = s;
  __syncthreads();
  long long acc = s;
  for (int off = 1; off < 256; off <<= 1) {
    long long add = (tid >= off) ? tsum[tid - off] : 0;
    __syncthreads();
    acc += add;
    tsum[tid] = acc;
    __syncthreads();
  }
  long long run = acc - s;   // exclusive prefix for this thread's bin range
  for (int q = 0; q < per; q++) {
    unsigned c = hist[tid * per + q];
    if (k >= run && k < run + (long long)c) { shOut[0] = (unsigned)(tid * per + q); shOut[1] = (unsigned)(k - run); }
    run += c;
  }
  __syncthreads();
}

// ---- row norms + ws zeroing + class/domain bucketing (block 0; y,l available at t=0) ----
__global__ __launch_bounds__(256) void xn_kernel(const float* __restrict__ sf,
                                                 const float* __restrict__ tf,
                                                 float* __restrict__ xn,
                                                 uint4* __restrict__ wsz,
                                                 const int* __restrict__ y,
                                                 const int* __restrict__ l,
                                                 int* __restrict__ perm,
                                                 int* __restrict__ meta,
                                                 float* __restrict__ scal) {
  __shared__ unsigned cl[64];
  __shared__ unsigned bs2[64];
  __shared__ unsigned cur[64];
  const int tid = threadIdx.x;
  if (blockIdx.x == 0) {
    uint4 z; z.x = 0; z.y = 0; z.z = 0; z.w = 0;
    for (int q = tid; q < ZERO_BYTES / 16; q += 256) wsz[q] = z;
    if (tid < 64) cl[tid] = 0;
    __syncthreads();
    for (int i = tid; i < N_TOT; i += 256) atomicAdd(&cl[y[i] * 2 + l[i]], 1u);
    __syncthreads();
    if (tid == 0) {
      unsigned run = 0;
      for (int b2 = 0; b2 < 62; b2++) { bs2[b2] = run; run += cl[b2]; }
      unsigned run2 = 0, cnt0 = 0;
      for (int c = 0; c < NCLASS; c++) {
        int n = (int)(cl[2 * c] + cl[2 * c + 1]);
        meta[c] = n; meta[32 + c] = (int)cl[2 * c]; meta[64 + c] = (int)bs2[2 * c];
        meta[96 + c] = (int)run2; run2 += (unsigned)(n * n);
        cnt0 += cl[2 * c];
      }
      scal[1] = (float)((double)cnt0 / (4096.0 * 4096.0));
      scal[2] = (float)((double)(N_TOT - cnt0) / (4096.0 * 4096.0));
    }
    __syncthreads();
    if (tid < 64) cur[tid] = bs2[tid];
    __syncthreads();
    for (int i = tid; i < N_TOT; i += 256) {
      int b2 = y[i] * 2 + l[i];
      unsigned pos = atomicAdd(&cur[b2], 1u);
      perm[pos] = i;
    }
  }
  int wid = tid >> 6, lane = tid & 63;
  int row = blockIdx.x * 4 + wid;
  const float* src = (row < N_SRC) ? (sf + (size_t)row * DIMF) : (tf + (size_t)(row - N_SRC) * DIMF);
  float4 v = ((const float4*)src)[lane];
  float s = v.x * v.x + v.y * v.y + v.z * v.z + v.w * v.w;
#pragma unroll
  for (int o = 32; o > 0; o >>= 1) s += __shfl_down(s, o, 64);
  if (lane == 0) xn[row] = s;
}

// ------- MERGED: blocks [0,528) = source pairwise sq-dists + fused hist0 (unchanged);
//         blocks [528, 528+105*31) = per-class K-block RAW distances (no sigma dep).
//         LDS union'd (41472 B both branches) -> occupancy unchanged. -------
__global__ __launch_bounds__(256) void distbuild_k(const float* __restrict__ sf,
                                                   const float* __restrict__ tf,
                                                   const float* __restrict__ xn,
                                                   float* __restrict__ Ds,
                                                   unsigned* __restrict__ h,
                                                   const int* __restrict__ perm,
                                                   const int* __restrict__ meta,
                                                   float* __restrict__ gK) {
  __shared__ __align__(16) char smem[41472];
  const int tx = threadIdx.x, ty = threadIdx.y;
  const int tid = ty * 16 + tx;

  if (blockIdx.x < DIST_BLKS) {
    // ================= dist branch (byte-identical logic to measured-best) =================
    float (*As)[68] = (float(*)[68])smem;                      // 4352 B
    float (*Bs)[68] = (float(*)[68])(smem + 4352);             // 4352 B
    unsigned (*lh)[4096] = (unsigned(*)[4096])(smem + 8704);   // 32768 B
    const int par = tid & 1;
    for (int q = tid; q < 8192; q += 256) lh[q >> 12][q & 4095] = 0;
    int b = blockIdx.x;
    int by = (int)((sqrtf(8.f * (float)b + 1.f) - 1.f) * 0.5f);
    while ((by + 1) * (by + 2) / 2 <= b) ++by;
    while (by * (by + 1) / 2 > b) --by;
    int bx = b - by * (by + 1) / 2;
    const int R = by * 64, C = bx * 64;
    const int si = tid >> 2, sq = tid & 3;
    float4 va = ((const float4*)(sf + (size_t)(R + si) * 256 + 0))[sq];
    float4 vb = ((const float4*)(sf + (size_t)(C + si) * 256 + 0))[sq];
    float acc[4][4] = {};
    for (int kc = 0; kc < 256; kc += 16) {
      As[sq * 4 + 0][si] = va.x; As[sq * 4 + 1][si] = va.y; As[sq * 4 + 2][si] = va.z; As[sq * 4 + 3][si] = va.w;
      Bs[sq * 4 + 0][si] = vb.x; Bs[sq * 4 + 1][si] = vb.y; Bs[sq * 4 + 2][si] = vb.z; Bs[sq * 4 + 3][si] = vb.w;
      __syncthreads();
      if (kc + 16 < 256) {
        va = ((const float4*)(sf + (size_t)(R + si) * 256 + kc + 16))[sq];
        vb = ((const float4*)(sf + (size_t)(C + si) * 256 + kc + 16))[sq];
      }
#pragma unroll
      for (int k = 0; k < 16; k++) {
        float4 a = *(const float4*)&As[k][ty * 4];
        float4 b2 = *(const float4*)&Bs[k][tx * 4];
        acc[0][0] += a.x * b2.x; acc[0][1] += a.x * b2.y; acc[0][2] += a.x * b2.z; acc[0][3] += a.x * b2.w;
        acc[1][0] += a.y * b2.x; acc[1][1] += a.y * b2.y; acc[1][2] += a.y * b2.z; acc[1][3] += a.y * b2.w;
        acc[2][0] += a.z * b2.x; acc[2][1] += a.z * b2.y; acc[2][2] += a.z * b2.z; acc[2][3] += a.z * b2.w;
        acc[3][0] += a.w * b2.x; acc[3][1] += a.w * b2.y; acc[3][2] += a.w * b2.z; acc[3][3] += a.w * b2.w;
      }
      __syncthreads();
    }
    int jbase = C + tx * 4;
    float xnj0 = xn[jbase + 0], xnj1 = xn[jbase + 1], xnj2 = xn[jbase + 2], xnj3 = xn[jbase + 3];
#pragma unroll
    for (int r = 0; r < 4; r++) {
      int i = R + ty * 4 + r;
      float xni = xn[i];
      float v[4];
      v[0] = fmaxf(xni + xnj0 - 2.f * acc[r][0], 0.f);
      v[1] = fmaxf(xni + xnj1 - 2.f * acc[r][1], 0.f);
      v[2] = fmaxf(xni + xnj2 - 2.f * acc[r][2], 0.f);
      v[3] = fmaxf(xni + xnj3 - 2.f * acc[r][3], 0.f);
      if (jbase + 3 < i) {
        float4 o; o.x = v[0]; o.y = v[1]; o.z = v[2]; o.w = v[3];
        ((float4*)&Ds[(size_t)i * 2048 + jbase])[0] = o;
        atomicAdd(&lh[par][__float_as_uint(v[0]) >> 20], 1u);
        atomicAdd(&lh[par][__float_as_uint(v[1]) >> 20], 1u);
        atomicAdd(&lh[par][__float_as_uint(v[2]) >> 20], 1u);
        atomicAdd(&lh[par][__float_as_uint(v[3]) >> 20], 1u);
      } else {
#pragma unroll
        for (int k = 0; k < 4; k++) {
          if (jbase + k < i) {
            Ds[(size_t)i * 2048 + jbase + k] = v[k];
            atomicAdd(&lh[par][__float_as_uint(v[k]) >> 20], 1u);
          }
        }
      }
    }
    __syncthreads();
    for (int q = tid; q < 4096; q += 256) {
      unsigned v = lh[0][q] + lh[1][q];
      if (v) atomicAdd(&h[q], v);
    }
  } else {
    // ================= build-d branch (storing RAW d) =================
    float (*As)[260] = (float(*)[260])smem;                    // 16640 B
    float (*Bs)[260] = (float(*)[260])(smem + 16640);          // 16640 B
    float (*ot)[17]  = (float(*)[17])(smem + 33280);           // 1088 B
    int* ra = (int*)(smem + 34368);                            // 64 B
    int* rb = (int*)(smem + 34432);                            // 64 B
    int b2 = blockIdx.x - DIST_BLKS;
    const int c = b2 / BUILD_TPC;
    int b = b2 - c * BUILD_TPC;
    const int n = meta[c];
    const int cs = meta[64 + c];
    const int bo = meta[96 + c];
    const int T = (n + 15) >> 4;
    if (b >= T * (T + 1) / 2) return;
    int by = (int)((sqrtf(8.f * (float)b + 1.f) - 1.f) * 0.5f);
    while ((by + 1) * (by + 2) / 2 <= b) ++by;
    while (by * (by + 1) / 2 > b) --by;
    int bx = b - by * (by + 1) / 2;
    const int i0 = by * 16, j0 = bx * 16;
    if (tid < 16) { int il = i0 + tid; ra[tid] = (il < n) ? perm[cs + il] : -1; }
    else if (tid < 32) { int jl = j0 + tid - 16; rb[tid - 16] = (jl < n) ? perm[cs + jl] : -1; }
    __syncthreads();
    for (int e = tid; e < 1024; e += 256) {
      int r = e >> 6, q = e & 63;
      int g = ra[r];
      if (g >= 0) {
        const float* src = (g < N_SRC) ? (sf + (size_t)g * DIMF) : (tf + (size_t)(g - N_SRC) * DIMF);
        ((float4*)&As[r][q * 4])[0] = ((const float4*)src)[q];
      }
      int g2 = rb[r];
      if (g2 >= 0) {
        const float* src = (g2 < N_SRC) ? (sf + (size_t)g2 * DIMF) : (tf + (size_t)(g2 - N_SRC) * DIMF);
        ((float4*)&Bs[r][q * 4])[0] = ((const float4*)src)[q];
      }
    }
    __syncthreads();
    int il = i0 + ty, jl = j0 + tx;
    float val = 0.f;
    if (il < n && jl < n) {
      float dot = 0.f;
      const float4* a4 = (const float4*)&As[ty][0];
      const float4* b4 = (const float4*)&Bs[tx][0];
#pragma unroll 16
      for (int q = 0; q < 64; q++) {
        float4 a = a4[q], bb = b4[q];
        dot += a.x * bb.x + a.y * bb.y + a.z * bb.z + a.w * bb.w;
      }
      int gi = ra[ty], gj = rb[tx];
      val = xn[gi] + xn[gj] - 2.f * dot;   // RAW d (exp applied in solver with sigma)
      gK[(size_t)bo + (size_t)il * n + jl] = val;
    }
    ot[ty][tx] = val;
    __syncthreads();
    if (by != bx) {
      int il2 = j0 + ty, jl2 = i0 + tx;
      if (il2 < n && jl2 < n) gK[(size_t)bo + (size_t)il2 * n + jl2] = ot[tx][ty];
    }
  }
}

__global__ __launch_bounds__(256) void scan0_k(const unsigned* __restrict__ h, unsigned* __restrict__ st) {
  __shared__ unsigned r0[2];
  __shared__ unsigned r1[2];
  scan_find(h, 4096, K_TRI1, r0, threadIdx.x);
  scan_find(h, 4096, K_TRI2, r1, threadIdx.x);
  if (threadIdx.x == 0) { st[0] = r0[0]; st[1] = r0[1]; st[2] = r1[0]; st[3] = r1[1]; }
}

// ---------------- radix pass 1 (triangle reads, sequential rows) ----------------
__global__ __launch_bounds__(256) void hist1_k(const float* __restrict__ Ds, const unsigned* __restrict__ st,
                                               unsigned* __restrict__ hA, unsigned* __restrict__ hB) {
  __shared__ unsigned lA[4096];
  __shared__ unsigned lB[4096];
  for (int i = threadIdx.x; i < 4096; i += 256) { lA[i] = 0; lB[i] = 0; }
  __syncthreads();
  unsigned s0 = st[0], s1 = st[2];
  int gw = (blockIdx.x * 256 + threadIdx.x) >> 6;
  int lane = threadIdx.x & 63;
  const float* row = Ds + (size_t)gw * 2048;
  for (int j = lane; j < gw; j += 64) {
    unsigned u = __float_as_uint(row[j]);
    unsigned hi = u >> 20, mid = (u >> 8) & 0xFFFu;
    if (hi == s0) atomicAdd(&lA[mid], 1u);
    if (hi == s1) atomicAdd(&lB[mid], 1u);
  }
  __syncthreads();
  for (int i = threadIdx.x; i < 4096; i += 256) {
    if (lA[i]) atomicAdd(&hA[i], lA[i]);
    if (lB[i]) atomicAdd(&hB[i], lB[i]);
  }
}

__global__ __launch_bounds__(256) void scan1_k(const unsigned* __restrict__ hA, const unsigned* __restrict__ hB,
                                               unsigned* __restrict__ st) {
  __shared__ unsigned r0[2];
  __shared__ unsigned r1[2];
  long long kA = (long long)st[1];
  long long kB = (long long)st[3];
  scan_find(hA, 4096, kA, r0, threadIdx.x);
  scan_find(hB, 4096, kB, r1, threadIdx.x);
  if (threadIdx.x == 0) { st[4] = r0[0]; st[5] = r0[1]; st[6] = r1[0]; st[7] = r1[1]; }
}

// ---------------- radix pass 2 (triangle reads, sequential rows) ----------------
__global__ __launch_bounds__(256) void hist2_k(const float* __restrict__ Ds, const unsigned* __restrict__ st,
                                               unsigned* __restrict__ hA, unsigned* __restrict__ hB) {
  __shared__ unsigned lA[256];
  __shared__ unsigned lB[256];
  lA[threadIdx.x] = 0; lB[threadIdx.x] = 0;
  __syncthreads();
  unsigned p0 = (st[0] << 12) | st[4];
  unsigned p1 = (st[2] << 12) | st[6];
  int gw = (blockIdx.x * 256 + threadIdx.x) >> 6;
  int lane = threadIdx.x & 63;
  const float* row = Ds + (size_t)gw * 2048;
  for (int j = lane; j < gw; j += 64) {
    unsigned u = __float_as_uint(row[j]);
    unsigned pre = u >> 8;
    if (pre == p0) atomicAdd(&lA[u & 0xFFu], 1u);
    if (pre == p1) atomicAdd(&lB[u & 0xFFu], 1u);
  }
  __syncthreads();
  if (lA[threadIdx.x]) atomicAdd(&hA[threadIdx.x], lA[threadIdx.x]);
  if (lB[threadIdx.x]) atomicAdd(&hB[threadIdx.x], lB[threadIdx.x]);
}

// ------- scan2: sigma only (bucketing lives in xn_kernel block 0) -------
__global__ __launch_bounds__(256) void scan2b_k(const unsigned* __restrict__ hA, const unsigned* __restrict__ hB,
                                                const unsigned* __restrict__ st, float* __restrict__ scal) {
  int tid = threadIdx.x;
  __shared__ unsigned r0[2];
  __shared__ unsigned r1[2];
  scan_find(hA, 256, (long long)st[5], r0, tid);
  scan_find(hB, 256, (long long)st[7], r1, tid);
  if (tid == 0) {
    unsigned v1 = (st[0] << 20) | (st[4] << 8) | r0[0];
    unsigned v2 = (st[2] << 20) | (st[6] << 8) | r1[0];
    scal[0] = 0.5f * (__uint_as_float(v1) + __uint_as_float(v2));  // sigma
  }
}

// ---------------- per-(class,domain) Newton-PCG + fused final (256 threads) ----------------
// R12 + this round: staging computes e=expf(-d/sigma) ONCE, writes it back to gK
// in-place (d=0/d=1 blocks write disjoint column ranges; replay-safe: distbuild
// rewrites raw d each iteration), accumulates bc row-sums in the same pass (rows
// [c0,c0+m) are exactly bc's entries), and final-eval reads exp'd f32 directly.
// expf count per thread: 245 -> 98.
__global__ __launch_bounds__(256) void solver_k(float* __restrict__ gK, const int* __restrict__ meta,
                                                const float* __restrict__ scal, double* __restrict__ acc,
                                                unsigned* __restrict__ tick, float* __restrict__ out) {
  const int c = blockIdx.x >> 1, d = blockIdx.x & 1;
  const int n = meta[c];
  const int m0 = meta[32 + c];
  const int m = d ? (n - m0) : m0;
  const int c0 = d ? m0 : 0;
  const int bo = meta[96 + c];
  const float gamma = scal[1 + d];
  const float inv_sig = 1.f / scal[0];
  const int tid = threadIdx.x;
  const int wv = tid >> 6, lane = tid & 63;

  __shared__ unsigned short Wl[MAXW * WPAD];   // 51968 B
  __shared__ float pS[4 * MAXM];
  __shared__ float pD[4 * MAXM];
  __shared__ float Av[MAXW];
  __shared__ float Sv[MAXW];
  __shared__ float Uv[MAXW];
  __shared__ float bc[MAXM];
  __shared__ float gv[MAXM];
  __shared__ float dgv[MAXM];
  __shared__ alignas(16) float th[128];
  __shared__ alignas(16) float pv[128];
  __shared__ alignas(16) float xv[128];
  __shared__ double red[16];
  __shared__ double gds[2];
  __shared__ float alf_s[2];
  __shared__ int cgst[2];

  float* K = gK + bo;
  const int st = n;
  const int mp2 = (m + 1) & ~1;
  const int mp4 = (m + 3) & ~3;
  const int iw0 = (n * wv) >> 2, iw1 = (n * (wv + 1)) >> 2;
  const int rq = tid >> 2, ql = tid & 3;

  // staging: exp in-place write-back + bf16 W + fused bc row-sums
  for (int i = rq; i < n; i += 64) {
    float* Kr = K + (size_t)i * st + c0;
    unsigned short* Wr = Wl + i * WPAD;
    const bool inbc = (i >= c0) && (i < c0 + m);
    float s = 0.f;
    for (int j = ql; j < m; j += 4) {
      float e = expf(-Kr[j] * inv_sig);
      Kr[j] = e;                           // in-place: final-eval reads exp'd f32
      s += e;
      unsigned u = __float_as_uint(e);
      u += 0x7fffu + ((u >> 16) & 1u);     // RNE to bf16
      Wr[j] = (unsigned short)(u >> 16);
    }
    if (inbc) {
      s += __shfl_xor(s, 1, 64);
      s += __shfl_xor(s, 2, 64);
      if (ql == 0) bc[i - c0] = s * (1.0f / 4096.0f);
    }
    if (ql == 0) for (int j = m; j < mp4; j++) Wr[j] = 0;
  }
  __syncthreads();
  for (int j = tid; j < 128; j += 256) { th[j] = 0.f; pv[j] = 0.f; xv[j] = 0.f; }
  __syncthreads();

  float av_r = 0.f;   // this thread's Av[tid] (n <= 224 < 256: one row per thread)

  for (int it = 0; it < 25; it++) {
    double o = 0.0;
    if (it == 0) {
      const float s0c = gamma * expf(-1.f);
      av_r = 0.f;
      for (int i = tid; i < n; i += 256) { Sv[i] = s0c; o += (double)s0c; }
    } else {
      // merged: Av matvec -> S -> obj contribution (b64 W reads, broadcast th)
      for (int i = tid; i < n; i += 256) {
        const unsigned short* Wr = Wl + i * WPAD;
        float a = 0.f;
#pragma unroll 4
        for (int j = 0; j < mp4; j += 4) {
          unsigned long long u = *(const unsigned long long*)(Wr + j);
          float4 t4 = *(const float4*)(th + j);
          unsigned lo = (unsigned)u, hi = (unsigned)(u >> 32);
          a += __uint_as_float(lo << 16) * t4.x
             + __uint_as_float(lo & 0xffff0000u) * t4.y
             + __uint_as_float(hi << 16) * t4.z
             + __uint_as_float(hi & 0xffff0000u) * t4.w;
        }
        av_r = a;
        float si = gamma * expf(fminf(a - 1.f, 30.f));
        Sv[i] = si; o += (double)si;
      }
      for (int j = tid; j < m; j += 256) {
        float t_ = th[j];
        o += (double)(-bc[j] * t_ + LAMBDA * t_ * t_);
      }
    }
    __syncthreads();
    // ---- gradient (+ Jacobi diag at it==0 only; frozen after) ----
    if (it == 0) {
      for (int j = lane; j < m; j += 64) {
        const unsigned short* Wc = Wl + j;
        float s_ = 0.f, ds_ = 0.f;
        int i = iw0;
        for (; i + 3 < iw1; i += 4) {
          float w0 = bf2f(Wc[(i + 0) * WPAD]), w1 = bf2f(Wc[(i + 1) * WPAD]);
          float w2 = bf2f(Wc[(i + 2) * WPAD]), w3 = bf2f(Wc[(i + 3) * WPAD]);
          float a0 = w0 * Sv[i], a1 = w1 * Sv[i + 1], a2 = w2 * Sv[i + 2], a3 = w3 * Sv[i + 3];
          s_ += a0 + a1 + a2 + a3;
          ds_ += a0 * w0 + a1 * w1 + a2 * w2 + a3 * w3;
        }
        for (; i < iw1; i++) { float w = bf2f(Wc[i * WPAD]); float a = w * Sv[i]; s_ += a; ds_ += a * w; }
        pS[wv * MAXM + j] = s_; pD[wv * MAXM + j] = ds_;
      }
    } else {
      for (int j = lane; j < m; j += 64) {
        const unsigned short* Wc = Wl + j;
        float s_ = 0.f;
        int i = iw0;
        for (; i + 3 < iw1; i += 4)
          s_ += bf2f(Wc[(i+0)*WPAD]) * Sv[i]   + bf2f(Wc[(i+1)*WPAD]) * Sv[i+1]
              + bf2f(Wc[(i+2)*WPAD]) * Sv[i+2] + bf2f(Wc[(i+3)*WPAD]) * Sv[i+3];
        for (; i < iw1; i++) s_ += bf2f(Wc[i * WPAD]) * Sv[i];
        pS[wv * MAXM + j] = s_;
      }
    }
    __syncthreads();
    double gm = 0.0;
    for (int j = tid; j < m; j += 256) {
      float s_ = pS[j] + pS[MAXM + j] + pS[2 * MAXM + j] + pS[3 * MAXM + j];
      if (it == 0) {
        float ds_ = pD[j] + pD[MAXM + j] + pD[2 * MAXM + j] + pD[3 * MAXM + j];
        dgv[j] = ds_ + 2.f * LAMBDA;
      }
      float g = s_ - bc[j] + 2.f * LAMBDA * th[j];
      gv[j] = g;
      double ag = fabs((double)g); if (ag > gm) gm = ag;
    }
    double obj, gmax;
    blockReduceSumMax(o, gm, red, obj, gmax);
    if (gmax < 1e-5) break;

    // ---- PCG solve H x = -g: state register-resident in wave 0 ----
    const float tolf = (it == 0) ? 1e-2f : ((it == 1) ? 1e-3f : 1e-4f);
    float p0 = 0.f, p1 = 0.f, r0 = 0.f, r1 = 0.f, z0 = 0.f, z1 = 0.f, x0 = 0.f, x1 = 0.f;
    float dg0 = 1.f, dg1 = 1.f, rzf = 0.f, rz0f = 0.f;
    float bq = 0.f, wp = 0.f;   // bq = (W x)[tid] accumulated; wp = (W p)[tid]
    double gtpacc = 0.0;   // block-uniform in wave0: sum of alpha_k * rz_k = -g^T x
    const int j0 = lane, j1 = lane + 64;
    if (wv == 0) {
      if (j0 < m) { dg0 = dgv[j0]; r0 = -gv[j0]; z0 = r0 / dg0; }
      if (j1 < m) { dg1 = dgv[j1]; r1 = -gv[j1]; z1 = r1 / dg1; }
      p0 = z0; p1 = z1;
      rzf = wredF(r0 * z0 + r1 * z1);
      rz0f = rzf;
      pv[j0] = p0; pv[j1] = p1;
      if (lane == 0) { cgst[0] = (rzf > 0.f) ? 0 : 1; cgst[1] = 0; }
    }
    __syncthreads();
    bool brk = false;
    for (int cg = 0; cg < 12; cg++) {
      // flush pending alpha from previous CG iter (wp still holds prev W.p)
      if (cgst[1]) bq += alf_s[0] * wp;
      if (cgst[0]) { brk = true; break; }
      // matvec1: Uv = Sv .* (W pv)  (one row per thread)
      for (int i = tid; i < n; i += 256) {
        const unsigned short* Wr = Wl + i * WPAD;
        float a = 0.f;
#pragma unroll 4
        for (int j = 0; j < mp4; j += 4) {
          unsigned long long u = *(const unsigned long long*)(Wr + j);
          float4 t4 = *(const float4*)(pv + j);
          unsigned lo = (unsigned)u, hi = (unsigned)(u >> 32);
          a += __uint_as_float(lo << 16) * t4.x
             + __uint_as_float(lo & 0xffff0000u) * t4.y
             + __uint_as_float(hi << 16) * t4.z
             + __uint_as_float(hi & 0xffff0000u) * t4.w;
        }
        wp = a;
        Uv[i] = a * Sv[i];
      }
      __syncthreads();
      // matvec2: per-wave partial q_j over this wave's i-range
      for (int j = lane; j < m; j += 64) {
        const unsigned short* Wc = Wl + j;
        float q = 0.f;
        int i = iw0;
        for (; i + 3 < iw1; i += 4)
          q += bf2f(Wc[(i+0)*WPAD]) * Uv[i]   + bf2f(Wc[(i+1)*WPAD]) * Uv[i+1]
             + bf2f(Wc[(i+2)*WPAD]) * Uv[i+2] + bf2f(Wc[(i+3)*WPAD]) * Uv[i+3];
        for (; i < iw1; i++) q += bf2f(Wc[i * WPAD]) * Uv[i];
        pS[wv * MAXM + j] = q;
      }
      __syncthreads();
      // epilogue: wave 0 combines partials, does all CG scalar work in-register
      if (wv == 0) {
        float q0 = 0.f, q1 = 0.f;
        if (j0 < m) q0 = pS[j0] + pS[MAXM + j0] + pS[2*MAXM + j0] + pS[3*MAXM + j0] + 2.f * LAMBDA * p0;
        if (j1 < m) q1 = pS[j1] + pS[MAXM + j1] + pS[2*MAXM + j1] + pS[3*MAXM + j1] + 2.f * LAMBDA * p1;
        float pq = wredF(p0 * q0 + p1 * q1);
        int stop = 0;
        if (!(pq > 0.f)) {
          stop = 1;
          if (lane == 0) cgst[1] = 0;
        } else {
          float alpha = rzf / pq;
          gtpacc += (double)alpha * (double)rzf;
          x0 += alpha * p0; x1 += alpha * p1;
          r0 -= alpha * q0; r1 -= alpha * q1;
          z0 = r0 / dg0;    z1 = r1 / dg1;
          if (lane == 0) { alf_s[0] = alpha; cgst[1] = 1; }
          float rzn = wredF(r0 * z0 + r1 * z1);
          if (rzn < tolf * rz0f || cg == 11) stop = 1;
          else {
            float beta = rzn / rzf;
            p0 = z0 + beta * p0; p1 = z1 + beta * p1;
            pv[j0] = p0; pv[j1] = p1;
            rzf = rzn;
          }
        }
        if (lane == 0) cgst[0] = stop;
      }
      __syncthreads();
    }
    // flush last pending alpha if loop exited without a top-of-loop flush
    if (!brk && cgst[1]) bq += alf_s[0] * wp;
    // publish x and gtp = g^T x = -gtpacc (exact CG identity)
    if (wv == 0) {
      xv[j0] = x0; xv[j1] = x1;
      if (lane == 0) gds[0] = -gtpacc;
    }
    __syncthreads();
    double gtp = gds[0];
    if (!(gtp < 0.0)) break;   // no CG progress => converged/degenerate

    float t = 1.f;
    if (-gtp >= 1e-4) {
      // line search: W.x is already in register bq — no matvec needed
      for (int ls = 0; ls < 10; ls++) {
        double ol = 0.0;
        if (tid < n) ol += (double)(gamma * expf(fminf(av_r + t * bq - 1.f, 30.f)));
        for (int j = tid; j < m; j += 256) {
          float tj = th[j] + t * xv[j];
          ol += (double)(-bc[j] * tj + LAMBDA * tj * tj);
        }
        double ot2 = blockReduceSum(ol, red);
        if (ot2 <= obj + 1e-4 * (double)t * gtp) break;
        t *= 0.5f;
      }
    }
    for (int j = tid; j < mp2; j += 256) th[j] += t * xv[j];
    __syncthreads();
  }

  // ---- final exact f32 evaluation (gK now holds exp'd f32 values), lane-quad coalesced ----
  __syncthreads();
  for (int i = rq; i < n; i += 64) {
    const float* Kr = K + (size_t)i * st + c0;
    float a = 0.f;
#pragma unroll 4
    for (int j = ql; j < m; j += 4) a += th[j] * Kr[j];
    a += __shfl_xor(a, 1, 64);
    a += __shfl_xor(a, 2, 64);
    if (ql == 0) Av[i] = a;
  }
  __syncthreads();
  double t1l = 0.0, t2l = 0.0;
  for (int i = tid; i < n; i += 256) t2l += (double)(gamma * expf(fminf(Av[i] - 1.f, 30.f)));
  for (int j = tid; j < m; j += 256) t1l += (double)(bc[j] * th[j]);
  double t1 = blockReduceSum(t1l, red);
  double t2 = blockReduceSum(t2l, red);
  if (tid == 0) {
    atomicAdd(&acc[0], t1);
    atomicAdd(&acc[1], t2);
    __threadfence();
    unsigned old = __hip_atomic_fetch_add(&tick[0], 1u, __ATOMIC_ACQ_REL, __HIP_MEMORY_SCOPE_AGENT);
    if (old == 61u) {
      double a0 = __hip_atomic_load(&acc[0], __ATOMIC_RELAXED, __HIP_MEMORY_SCOPE_AGENT);
      double a1 = __hip_atomic_load(&acc[1], __ATOMIC_RELAXED, __HIP_MEMORY_SCOPE_AGENT);
      out[0] = (float)(a0 - a1);
    }
  }
}

// ---------------- launcher (8 nodes) ----------------
extern "C" void kernel_launch(void* const* d_in, const int* in_sizes, int n_in,
                              void* d_out, int out_size, void* d_ws, size_t ws_size,
                              hipStream_t stream) {
  const float* sf = (const float*)d_in[0];
  const float* tf = (const float*)d_in[1];
  const int* y = (const int*)d_in[2];
  const int* l = (const int*)d_in[3];
  char* ws = (char*)d_ws;

  double*   acc    = (double*)(ws + WS_ACC);
  unsigned* hist0  = (unsigned*)(ws + WS_HIST0);
  unsigned* histA  = (unsigned*)(ws + WS_HISTA);
  unsigned* histB  = (unsigned*)(ws + WS_HISTB);
  unsigned* h2A    = (unsigned*)(ws + WS_H2A);
  unsigned* h2B    = (unsigned*)(ws + WS_H2B);
  unsigned* state  = (unsigned*)(ws + WS_STATE);
  unsigned* tick   = (unsigned*)(ws + WS_TICK);
  int*      meta   = (int*)(ws + WS_META);
  float*    scal   = (float*)(ws + WS_SCAL);
  int*      perm   = (int*)(ws + WS_PERM);
  float*    xnp    = (float*)(ws + WS_XN);
  float*    Ds     = (float*)(ws + WS_DS);
  float*    gK     = (float*)(ws + WS_KBLK);

  hipLaunchKernelGGL(xn_kernel, dim3(1024), dim3(256), 0, stream, sf, tf, xnp, (uint4*)ws, y, l, perm, meta, scal);
  hipLaunchKernelGGL(distbuild_k, dim3(DIST_BLKS + BUILD_TPC * NCLASS), dim3(16, 16), 0, stream,
                     sf, tf, xnp, Ds, hist0, perm, meta, gK);
  hipLaunchKernelGGL(scan0_k, dim3(1), dim3(256), 0, stream, hist0, state);
  hipLaunchKernelGGL(hist1_k, dim3(512), dim3(256), 0, stream, Ds, state, histA, histB);
  hipLaunchKernelGGL(scan1_k, dim3(1), dim3(256), 0, stream, histA, histB, state);
  hipLaunchKernelGGL(hist2_k, dim3(512), dim3(256), 0, stream, Ds, state, h2A, h2B);
  hipLaunchKernelGGL(scan2b_k, dim3(1), dim3(256), 0, stream, h2A, h2B, state, scal);
  hipLaunchKernelGGL(solver_k, dim3(62), dim3(256), 0, stream, gK, meta, scal, acc, tick, (float*)d_out);
}

// Round 14
// 206.768 us; speedup vs baseline: 1.0010x; 1.0010x over previous
//
#include <hip/hip_runtime.h>
#include <math.h>

#define N_TOT   4096
#define N_SRC   2048
#define DIMF    256
#define NCLASS  31
#define LAMBDA  0.01f

// median target ranks among the 2,096,128 strict-lower-triangle values.
#define K_TRI1  1048063LL
#define K_TRI2  1048064LL

// ---- ws layout (bytes) ----
#define WS_ACC    0           // 2 doubles
#define WS_HIST0  64          // 4096 u32
#define WS_HISTA  16448       // 4096 u32
#define WS_HISTB  32832       // 4096 u32
#define WS_H2A    49216       // 256 u32
#define WS_H2B    50240       // 256 u32
#define WS_STATE  51264       // 64 u32 (st[0..7])
#define WS_TICK   51520       // 4 u32 (solver final ticket)
#define WS_META   52288       // 128 i32: ncls[32], m0c[32], cstart[32], blkoff[32]
#define WS_SCAL   52800       // 16 f32: [0]=sigma, [1]=gamma0, [2]=gamma1
#define ZERO_BYTES 53248
#define WS_PERM   53248       // 4096 i32
#define WS_XN     69632       // 4096 f32
#define WS_DS     1048576     // 2048*2048 f32 (lower triangle used)
#define WS_KBLK   17825792    // class K blocks (8 MB); holds RAW d (read-only in solver)

#define MAXW 224
#define MAXM 112
#define WPAD 116   // u16 row stride = 58 dwords: rows 8B-aligned (b64 reads);
                   // column reads: 64 lanes x 2B = 128B = 32 banks, 2 lanes/bank (free, m136)

#define DIST_BLKS 528
#define BUILD_TPC 105   // tiles per class: T<=14 -> T(T+1)/2 <= 105

__device__ __forceinline__ float bf2f(unsigned short h) {
  return __uint_as_float(((unsigned)h) << 16);
}

// f32 butterfly reduce across one wave (all lanes get the sum)
__device__ __forceinline__ float wredF(float v) {
#pragma unroll
  for (int o = 1; o < 64; o <<= 1) v += __shfl_xor(v, o, 64);
  return v;
}

// ---------------- reductions (256 threads) ----------------
__device__ __forceinline__ double blockReduceSum(double v, double* red) {
#pragma unroll
  for (int o = 32; o > 0; o >>= 1) v += __shfl_down(v, o, 64);
  int w = threadIdx.x >> 6, lane = threadIdx.x & 63;
  __syncthreads();
  if (lane == 0) red[w] = v;
  __syncthreads();
  return red[0] + red[1] + red[2] + red[3];
}

__device__ __forceinline__ void blockReduceSumMax(double s, double mx, double* red,
                                                  double& os, double& om) {
#pragma unroll
  for (int o = 32; o > 0; o >>= 1) {
    s += __shfl_down(s, o, 64);
    double u = __shfl_down(mx, o, 64);
    mx = fmax(mx, u);
  }
  int w = threadIdx.x >> 6, lane = threadIdx.x & 63;
  __syncthreads();
  if (lane == 0) { red[w] = s; red[4 + w] = mx; }
  __syncthreads();
  os = red[0] + red[1] + red[2] + red[3];
  om = fmax(fmax(red[4], red[5]), fmax(red[6], red[7]));
}

// scan over histogram (256 threads) — parallel Hillis-Steele prefix scan (measured-best)
__device__ void scan_find(const unsigned* hist, int nbins, long long k, unsigned* shOut, int tid) {
  __shared__ long long tsum[256];
  int per = nbins / 256;
  long long s = 0;
  for (int q = 0; q < per; q++) s += hist[tid * per + q];
  tsum[tid] = s;
  __syncthreads();
  long long acc = s;
  for (int off = 1; off < 256; off <<= 1) {
    long long add = (tid >= off) ? tsum[tid - off] : 0;
    __syncthreads();
    acc += add;
    tsum[tid] = acc;
    __syncthreads();
  }
  long long run = acc - s;   // exclusive prefix for this thread's bin range
  for (int q = 0; q < per; q++) {
    unsigned c = hist[tid * per + q];
    if (k >= run && k < run + (long long)c) { shOut[0] = (unsigned)(tid * per + q); shOut[1] = (unsigned)(k - run); }
    run += c;
  }
  __syncthreads();
}

// ---- row norms + ws zeroing + class/domain bucketing (block 0; y,l available at t=0) ----
__global__ __launch_bounds__(256) void xn_kernel(const float* __restrict__ sf,
                                                 const float* __restrict__ tf,
                                                 float* __restrict__ xn,
                                                 uint4* __restrict__ wsz,
                                                 const int* __restrict__ y,
                                                 const int* __restrict__ l,
                                                 int* __restrict__ perm,
                                                 int* __restrict__ meta,
                                                 float* __restrict__ scal) {
  __shared__ unsigned cl[64];
  __shared__ unsigned bs2[64];
  __shared__ unsigned cur[64];
  const int tid = threadIdx.x;
  if (blockIdx.x == 0) {
    uint4 z; z.x = 0; z.y = 0; z.z = 0; z.w = 0;
    for (int q = tid; q < ZERO_BYTES / 16; q += 256) wsz[q] = z;
    if (tid < 64) cl[tid] = 0;
    __syncthreads();
    for (int i = tid; i < N_TOT; i += 256) atomicAdd(&cl[y[i] * 2 + l[i]], 1u);
    __syncthreads();
    if (tid == 0) {
      unsigned run = 0;
      for (int b2 = 0; b2 < 62; b2++) { bs2[b2] = run; run += cl[b2]; }
      unsigned run2 = 0, cnt0 = 0;
      for (int c = 0; c < NCLASS; c++) {
        int n = (int)(cl[2 * c] + cl[2 * c + 1]);
        meta[c] = n; meta[32 + c] = (int)cl[2 * c]; meta[64 + c] = (int)bs2[2 * c];
        meta[96 + c] = (int)run2; run2 += (unsigned)(n * n);
        cnt0 += cl[2 * c];
      }
      scal[1] = (float)((double)cnt0 / (4096.0 * 4096.0));
      scal[2] = (float)((double)(N_TOT - cnt0) / (4096.0 * 4096.0));
    }
    __syncthreads();
    if (tid < 64) cur[tid] = bs2[tid];
    __syncthreads();
    for (int i = tid; i < N_TOT; i += 256) {
      int b2 = y[i] * 2 + l[i];
      unsigned pos = atomicAdd(&cur[b2], 1u);
      perm[pos] = i;
    }
  }
  int wid = tid >> 6, lane = tid & 63;
  int row = blockIdx.x * 4 + wid;
  const float* src = (row < N_SRC) ? (sf + (size_t)row * DIMF) : (tf + (size_t)(row - N_SRC) * DIMF);
  float4 v = ((const float4*)src)[lane];
  float s = v.x * v.x + v.y * v.y + v.z * v.z + v.w * v.w;
#pragma unroll
  for (int o = 32; o > 0; o >>= 1) s += __shfl_down(s, o, 64);
  if (lane == 0) xn[row] = s;
}

// ------- MERGED: blocks [0,528) = source pairwise sq-dists + fused hist0 (unchanged);
//         blocks [528, 528+105*31) = per-class K-block RAW distances (no sigma dep).
//         LDS union'd (41472 B both branches) -> occupancy unchanged. -------
__global__ __launch_bounds__(256) void distbuild_k(const float* __restrict__ sf,
                                                   const float* __restrict__ tf,
                                                   const float* __restrict__ xn,
                                                   float* __restrict__ Ds,
                                                   unsigned* __restrict__ h,
                                                   const int* __restrict__ perm,
                                                   const int* __restrict__ meta,
                                                   float* __restrict__ gK) {
  __shared__ __align__(16) char smem[41472];
  const int tx = threadIdx.x, ty = threadIdx.y;
  const int tid = ty * 16 + tx;

  if (blockIdx.x < DIST_BLKS) {
    // ================= dist branch (byte-identical logic to measured-best) =================
    float (*As)[68] = (float(*)[68])smem;                      // 4352 B
    float (*Bs)[68] = (float(*)[68])(smem + 4352);             // 4352 B
    unsigned (*lh)[4096] = (unsigned(*)[4096])(smem + 8704);   // 32768 B
    const int par = tid & 1;
    for (int q = tid; q < 8192; q += 256) lh[q >> 12][q & 4095] = 0;
    int b = blockIdx.x;
    int by = (int)((sqrtf(8.f * (float)b + 1.f) - 1.f) * 0.5f);
    while ((by + 1) * (by + 2) / 2 <= b) ++by;
    while (by * (by + 1) / 2 > b) --by;
    int bx = b - by * (by + 1) / 2;
    const int R = by * 64, C = bx * 64;
    const int si = tid >> 2, sq = tid & 3;
    float4 va = ((const float4*)(sf + (size_t)(R + si) * 256 + 0))[sq];
    float4 vb = ((const float4*)(sf + (size_t)(C + si) * 256 + 0))[sq];
    float acc[4][4] = {};
    for (int kc = 0; kc < 256; kc += 16) {
      As[sq * 4 + 0][si] = va.x; As[sq * 4 + 1][si] = va.y; As[sq * 4 + 2][si] = va.z; As[sq * 4 + 3][si] = va.w;
      Bs[sq * 4 + 0][si] = vb.x; Bs[sq * 4 + 1][si] = vb.y; Bs[sq * 4 + 2][si] = vb.z; Bs[sq * 4 + 3][si] = vb.w;
      __syncthreads();
      if (kc + 16 < 256) {
        va = ((const float4*)(sf + (size_t)(R + si) * 256 + kc + 16))[sq];
        vb = ((const float4*)(sf + (size_t)(C + si) * 256 + kc + 16))[sq];
      }
#pragma unroll
      for (int k = 0; k < 16; k++) {
        float4 a = *(const float4*)&As[k][ty * 4];
        float4 b2 = *(const float4*)&Bs[k][tx * 4];
        acc[0][0] += a.x * b2.x; acc[0][1] += a.x * b2.y; acc[0][2] += a.x * b2.z; acc[0][3] += a.x * b2.w;
        acc[1][0] += a.y * b2.x; acc[1][1] += a.y * b2.y; acc[1][2] += a.y * b2.z; acc[1][3] += a.y * b2.w;
        acc[2][0] += a.z * b2.x; acc[2][1] += a.z * b2.y; acc[2][2] += a.z * b2.z; acc[2][3] += a.z * b2.w;
        acc[3][0] += a.w * b2.x; acc[3][1] += a.w * b2.y; acc[3][2] += a.w * b2.z; acc[3][3] += a.w * b2.w;
      }
      __syncthreads();
    }
    int jbase = C + tx * 4;
    float xnj0 = xn[jbase + 0], xnj1 = xn[jbase + 1], xnj2 = xn[jbase + 2], xnj3 = xn[jbase + 3];
#pragma unroll
    for (int r = 0; r < 4; r++) {
      int i = R + ty * 4 + r;
      float xni = xn[i];
      float v[4];
      v[0] = fmaxf(xni + xnj0 - 2.f * acc[r][0], 0.f);
      v[1] = fmaxf(xni + xnj1 - 2.f * acc[r][1], 0.f);
      v[2] = fmaxf(xni + xnj2 - 2.f * acc[r][2], 0.f);
      v[3] = fmaxf(xni + xnj3 - 2.f * acc[r][3], 0.f);
      if (jbase + 3 < i) {
        float4 o; o.x = v[0]; o.y = v[1]; o.z = v[2]; o.w = v[3];
        ((float4*)&Ds[(size_t)i * 2048 + jbase])[0] = o;
        atomicAdd(&lh[par][__float_as_uint(v[0]) >> 20], 1u);
        atomicAdd(&lh[par][__float_as_uint(v[1]) >> 20], 1u);
        atomicAdd(&lh[par][__float_as_uint(v[2]) >> 20], 1u);
        atomicAdd(&lh[par][__float_as_uint(v[3]) >> 20], 1u);
      } else {
#pragma unroll
        for (int k = 0; k < 4; k++) {
          if (jbase + k < i) {
            Ds[(size_t)i * 2048 + jbase + k] = v[k];
            atomicAdd(&lh[par][__float_as_uint(v[k]) >> 20], 1u);
          }
        }
      }
    }
    __syncthreads();
    for (int q = tid; q < 4096; q += 256) {
      unsigned v = lh[0][q] + lh[1][q];
      if (v) atomicAdd(&h[q], v);
    }
  } else {
    // ================= build-d branch (storing RAW d) =================
    float (*As)[260] = (float(*)[260])smem;                    // 16640 B
    float (*Bs)[260] = (float(*)[260])(smem + 16640);          // 16640 B
    float (*ot)[17]  = (float(*)[17])(smem + 33280);           // 1088 B
    int* ra = (int*)(smem + 34368);                            // 64 B
    int* rb = (int*)(smem + 34432);                            // 64 B
    int b2 = blockIdx.x - DIST_BLKS;
    const int c = b2 / BUILD_TPC;
    int b = b2 - c * BUILD_TPC;
    const int n = meta[c];
    const int cs = meta[64 + c];
    const int bo = meta[96 + c];
    const int T = (n + 15) >> 4;
    if (b >= T * (T + 1) / 2) return;
    int by = (int)((sqrtf(8.f * (float)b + 1.f) - 1.f) * 0.5f);
    while ((by + 1) * (by + 2) / 2 <= b) ++by;
    while (by * (by + 1) / 2 > b) --by;
    int bx = b - by * (by + 1) / 2;
    const int i0 = by * 16, j0 = bx * 16;
    if (tid < 16) { int il = i0 + tid; ra[tid] = (il < n) ? perm[cs + il] : -1; }
    else if (tid < 32) { int jl = j0 + tid - 16; rb[tid - 16] = (jl < n) ? perm[cs + jl] : -1; }
    __syncthreads();
    for (int e = tid; e < 1024; e += 256) {
      int r = e >> 6, q = e & 63;
      int g = ra[r];
      if (g >= 0) {
        const float* src = (g < N_SRC) ? (sf + (size_t)g * DIMF) : (tf + (size_t)(g - N_SRC) * DIMF);
        ((float4*)&As[r][q * 4])[0] = ((const float4*)src)[q];
      }
      int g2 = rb[r];
      if (g2 >= 0) {
        const float* src = (g2 < N_SRC) ? (sf + (size_t)g2 * DIMF) : (tf + (size_t)(g2 - N_SRC) * DIMF);
        ((float4*)&Bs[r][q * 4])[0] = ((const float4*)src)[q];
      }
    }
    __syncthreads();
    int il = i0 + ty, jl = j0 + tx;
    float val = 0.f;
    if (il < n && jl < n) {
      float dot = 0.f;
      const float4* a4 = (const float4*)&As[ty][0];
      const float4* b4 = (const float4*)&Bs[tx][0];
#pragma unroll 16
      for (int q = 0; q < 64; q++) {
        float4 a = a4[q], bb = b4[q];
        dot += a.x * bb.x + a.y * bb.y + a.z * bb.z + a.w * bb.w;
      }
      int gi = ra[ty], gj = rb[tx];
      val = xn[gi] + xn[gj] - 2.f * dot;   // RAW d (exp applied in solver with sigma)
      gK[(size_t)bo + (size_t)il * n + jl] = val;
    }
    ot[ty][tx] = val;
    __syncthreads();
    if (by != bx) {
      int il2 = j0 + ty, jl2 = i0 + tx;
      if (il2 < n && jl2 < n) gK[(size_t)bo + (size_t)il2 * n + jl2] = ot[tx][ty];
    }
  }
}

__global__ __launch_bounds__(256) void scan0_k(const unsigned* __restrict__ h, unsigned* __restrict__ st) {
  __shared__ unsigned r0[2];
  __shared__ unsigned r1[2];
  scan_find(h, 4096, K_TRI1, r0, threadIdx.x);
  scan_find(h, 4096, K_TRI2, r1, threadIdx.x);
  if (threadIdx.x == 0) { st[0] = r0[0]; st[1] = r0[1]; st[2] = r1[0]; st[3] = r1[1]; }
}

// ---------------- radix pass 1 (triangle reads, sequential rows) ----------------
__global__ __launch_bounds__(256) void hist1_k(const float* __restrict__ Ds, const unsigned* __restrict__ st,
                                               unsigned* __restrict__ hA, unsigned* __restrict__ hB) {
  __shared__ unsigned lA[4096];
  __shared__ unsigned lB[4096];
  for (int i = threadIdx.x; i < 4096; i += 256) { lA[i] = 0; lB[i] = 0; }
  __syncthreads();
  unsigned s0 = st[0], s1 = st[2];
  int gw = (blockIdx.x * 256 + threadIdx.x) >> 6;
  int lane = threadIdx.x & 63;
  const float* row = Ds + (size_t)gw * 2048;
  for (int j = lane; j < gw; j += 64) {
    unsigned u = __float_as_uint(row[j]);
    unsigned hi = u >> 20, mid = (u >> 8) & 0xFFFu;
    if (hi == s0) atomicAdd(&lA[mid], 1u);
    if (hi == s1) atomicAdd(&lB[mid], 1u);
  }
  __syncthreads();
  for (int i = threadIdx.x; i < 4096; i += 256) {
    if (lA[i]) atomicAdd(&hA[i], lA[i]);
    if (lB[i]) atomicAdd(&hB[i], lB[i]);
  }
}

__global__ __launch_bounds__(256) void scan1_k(const unsigned* __restrict__ hA, const unsigned* __restrict__ hB,
                                               unsigned* __restrict__ st) {
  __shared__ unsigned r0[2];
  __shared__ unsigned r1[2];
  long long kA = (long long)st[1];
  long long kB = (long long)st[3];
  scan_find(hA, 4096, kA, r0, threadIdx.x);
  scan_find(hB, 4096, kB, r1, threadIdx.x);
  if (threadIdx.x == 0) { st[4] = r0[0]; st[5] = r0[1]; st[6] = r1[0]; st[7] = r1[1]; }
}

// ---------------- radix pass 2 (triangle reads, sequential rows) ----------------
__global__ __launch_bounds__(256) void hist2_k(const float* __restrict__ Ds, const unsigned* __restrict__ st,
                                               unsigned* __restrict__ hA, unsigned* __restrict__ hB) {
  __shared__ unsigned lA[256];
  __shared__ unsigned lB[256];
  lA[threadIdx.x] = 0; lB[threadIdx.x] = 0;
  __syncthreads();
  unsigned p0 = (st[0] << 12) | st[4];
  unsigned p1 = (st[2] << 12) | st[6];
  int gw = (blockIdx.x * 256 + threadIdx.x) >> 6;
  int lane = threadIdx.x & 63;
  const float* row = Ds + (size_t)gw * 2048;
  for (int j = lane; j < gw; j += 64) {
    unsigned u = __float_as_uint(row[j]);
    unsigned pre = u >> 8;
    if (pre == p0) atomicAdd(&lA[u & 0xFFu], 1u);
    if (pre == p1) atomicAdd(&lB[u & 0xFFu], 1u);
  }
  __syncthreads();
  if (lA[threadIdx.x]) atomicAdd(&hA[threadIdx.x], lA[threadIdx.x]);
  if (lB[threadIdx.x]) atomicAdd(&hB[threadIdx.x], lB[threadIdx.x]);
}

// ------- scan2: sigma only (bucketing lives in xn_kernel block 0) -------
__global__ __launch_bounds__(256) void scan2b_k(const unsigned* __restrict__ hA, const unsigned* __restrict__ hB,
                                                const unsigned* __restrict__ st, float* __restrict__ scal) {
  int tid = threadIdx.x;
  __shared__ unsigned r0[2];
  __shared__ unsigned r1[2];
  scan_find(hA, 256, (long long)st[5], r0, tid);
  scan_find(hB, 256, (long long)st[7], r1, tid);
  if (tid == 0) {
    unsigned v1 = (st[0] << 20) | (st[4] << 8) | r0[0];
    unsigned v2 = (st[2] << 20) | (st[6] << 8) | r1[0];
    scal[0] = 0.5f * (__uint_as_float(v1) + __uint_as_float(v2));  // sigma
  }
}

// ---------------- per-(class,domain) Newton-PCG + fused final (256 threads) ----------------
// R12 (measured 200.2) + bc fused into staging ONLY (no gK write-back: R13's
// in-place store exploded WRITE_SIZE 5.8KB->2.3MB, +7us). Staging rows [c0,c0+m)
// are exactly bc's entries -> accumulate row-sum during staging, publish via
// 2-shfl quad combine. Deletes bc's separate global-read + 49-expf pass with zero
// added traffic. expf/thread: 245 -> 196.
__global__ __launch_bounds__(256) void solver_k(const float* __restrict__ gK, const int* __restrict__ meta,
                                                const float* __restrict__ scal, double* __restrict__ acc,
                                                unsigned* __restrict__ tick, float* __restrict__ out) {
  const int c = blockIdx.x >> 1, d = blockIdx.x & 1;
  const int n = meta[c];
  const int m0 = meta[32 + c];
  const int m = d ? (n - m0) : m0;
  const int c0 = d ? m0 : 0;
  const int bo = meta[96 + c];
  const float gamma = scal[1 + d];
  const float inv_sig = 1.f / scal[0];
  const int tid = threadIdx.x;
  const int wv = tid >> 6, lane = tid & 63;

  __shared__ unsigned short Wl[MAXW * WPAD];   // 51968 B
  __shared__ float pS[4 * MAXM];
  __shared__ float pD[4 * MAXM];
  __shared__ float Av[MAXW];
  __shared__ float Sv[MAXW];
  __shared__ float Uv[MAXW];
  __shared__ float bc[MAXM];
  __shared__ float gv[MAXM];
  __shared__ float dgv[MAXM];
  __shared__ alignas(16) float th[128];
  __shared__ alignas(16) float pv[128];
  __shared__ alignas(16) float xv[128];
  __shared__ double red[16];
  __shared__ double gds[2];
  __shared__ float alf_s[2];
  __shared__ int cgst[2];

  const float* K = gK + bo;
  const int st = n;
  const int mp2 = (m + 1) & ~1;
  const int mp4 = (m + 3) & ~3;
  const int iw0 = (n * wv) >> 2, iw1 = (n * (wv + 1)) >> 2;
  const int rq = tid >> 2, ql = tid & 3;

  // staging: exp inline (no write-back) + bf16 W + fused bc row-sums
  for (int i = rq; i < n; i += 64) {
    const float* Kr = K + (size_t)i * st + c0;
    unsigned short* Wr = Wl + i * WPAD;
    const bool inbc = (i >= c0) && (i < c0 + m);
    float s = 0.f;
    for (int j = ql; j < m; j += 4) {
      float e = expf(-Kr[j] * inv_sig);
      s += e;
      unsigned u = __float_as_uint(e);
      u += 0x7fffu + ((u >> 16) & 1u);     // RNE to bf16
      Wr[j] = (unsigned short)(u >> 16);
    }
    if (inbc) {
      s += __shfl_xor(s, 1, 64);
      s += __shfl_xor(s, 2, 64);
      if (ql == 0) bc[i - c0] = s * (1.0f / 4096.0f);
    }
    if (ql == 0) for (int j = m; j < mp4; j++) Wr[j] = 0;
  }
  __syncthreads();
  for (int j = tid; j < 128; j += 256) { th[j] = 0.f; pv[j] = 0.f; xv[j] = 0.f; }
  __syncthreads();

  float av_r = 0.f;   // this thread's Av[tid] (n <= 224 < 256: one row per thread)

  for (int it = 0; it < 25; it++) {
    double o = 0.0;
    if (it == 0) {
      const float s0c = gamma * expf(-1.f);
      av_r = 0.f;
      for (int i = tid; i < n; i += 256) { Sv[i] = s0c; o += (double)s0c; }
    } else {
      // merged: Av matvec -> S -> obj contribution (b64 W reads, broadcast th)
      for (int i = tid; i < n; i += 256) {
        const unsigned short* Wr = Wl + i * WPAD;
        float a = 0.f;
#pragma unroll 4
        for (int j = 0; j < mp4; j += 4) {
          unsigned long long u = *(const unsigned long long*)(Wr + j);
          float4 t4 = *(const float4*)(th + j);
          unsigned lo = (unsigned)u, hi = (unsigned)(u >> 32);
          a += __uint_as_float(lo << 16) * t4.x
             + __uint_as_float(lo & 0xffff0000u) * t4.y
             + __uint_as_float(hi << 16) * t4.z
             + __uint_as_float(hi & 0xffff0000u) * t4.w;
        }
        av_r = a;
        float si = gamma * expf(fminf(a - 1.f, 30.f));
        Sv[i] = si; o += (double)si;
      }
      for (int j = tid; j < m; j += 256) {
        float t_ = th[j];
        o += (double)(-bc[j] * t_ + LAMBDA * t_ * t_);
      }
    }
    __syncthreads();
    // ---- gradient (+ Jacobi diag at it==0 only; frozen after) ----
    if (it == 0) {
      for (int j = lane; j < m; j += 64) {
        const unsigned short* Wc = Wl + j;
        float s_ = 0.f, ds_ = 0.f;
        int i = iw0;
        for (; i + 3 < iw1; i += 4) {
          float w0 = bf2f(Wc[(i + 0) * WPAD]), w1 = bf2f(Wc[(i + 1) * WPAD]);
          float w2 = bf2f(Wc[(i + 2) * WPAD]), w3 = bf2f(Wc[(i + 3) * WPAD]);
          float a0 = w0 * Sv[i], a1 = w1 * Sv[i + 1], a2 = w2 * Sv[i + 2], a3 = w3 * Sv[i + 3];
          s_ += a0 + a1 + a2 + a3;
          ds_ += a0 * w0 + a1 * w1 + a2 * w2 + a3 * w3;
        }
        for (; i < iw1; i++) { float w = bf2f(Wc[i * WPAD]); float a = w * Sv[i]; s_ += a; ds_ += a * w; }
        pS[wv * MAXM + j] = s_; pD[wv * MAXM + j] = ds_;
      }
    } else {
      for (int j = lane; j < m; j += 64) {
        const unsigned short* Wc = Wl + j;
        float s_ = 0.f;
        int i = iw0;
        for (; i + 3 < iw1; i += 4)
          s_ += bf2f(Wc[(i+0)*WPAD]) * Sv[i]   + bf2f(Wc[(i+1)*WPAD]) * Sv[i+1]
              + bf2f(Wc[(i+2)*WPAD]) * Sv[i+2] + bf2f(Wc[(i+3)*WPAD]) * Sv[i+3];
        for (; i < iw1; i++) s_ += bf2f(Wc[i * WPAD]) * Sv[i];
        pS[wv * MAXM + j] = s_;
      }
    }
    __syncthreads();
    double gm = 0.0;
    for (int j = tid; j < m; j += 256) {
      float s_ = pS[j] + pS[MAXM + j] + pS[2 * MAXM + j] + pS[3 * MAXM + j];
      if (it == 0) {
        float ds_ = pD[j] + pD[MAXM + j] + pD[2 * MAXM + j] + pD[3 * MAXM + j];
        dgv[j] = ds_ + 2.f * LAMBDA;
      }
      float g = s_ - bc[j] + 2.f * LAMBDA * th[j];
      gv[j] = g;
      double ag = fabs((double)g); if (ag > gm) gm = ag;
    }
    double obj, gmax;
    blockReduceSumMax(o, gm, red, obj, gmax);
    if (gmax < 1e-5) break;

    // ---- PCG solve H x = -g: state register-resident in wave 0 ----
    const float tolf = (it == 0) ? 1e-2f : ((it == 1) ? 1e-3f : 1e-4f);
    float p0 = 0.f, p1 = 0.f, r0 = 0.f, r1 = 0.f, z0 = 0.f, z1 = 0.f, x0 = 0.f, x1 = 0.f;
    float dg0 = 1.f, dg1 = 1.f, rzf = 0.f, rz0f = 0.f;
    float bq = 0.f, wp = 0.f;   // bq = (W x)[tid] accumulated; wp = (W p)[tid]
    double gtpacc = 0.0;   // block-uniform in wave0: sum of alpha_k * rz_k = -g^T x
    const int j0 = lane, j1 = lane + 64;
    if (wv == 0) {
      if (j0 < m) { dg0 = dgv[j0]; r0 = -gv[j0]; z0 = r0 / dg0; }
      if (j1 < m) { dg1 = dgv[j1]; r1 = -gv[j1]; z1 = r1 / dg1; }
      p0 = z0; p1 = z1;
      rzf = wredF(r0 * z0 + r1 * z1);
      rz0f = rzf;
      pv[j0] = p0; pv[j1] = p1;
      if (lane == 0) { cgst[0] = (rzf > 0.f) ? 0 : 1; cgst[1] = 0; }
    }
    __syncthreads();
    bool brk = false;
    for (int cg = 0; cg < 12; cg++) {
      // flush pending alpha from previous CG iter (wp still holds prev W.p)
      if (cgst[1]) bq += alf_s[0] * wp;
      if (cgst[0]) { brk = true; break; }
      // matvec1: Uv = Sv .* (W pv)  (one row per thread)
      for (int i = tid; i < n; i += 256) {
        const unsigned short* Wr = Wl + i * WPAD;
        float a = 0.f;
#pragma unroll 4
        for (int j = 0; j < mp4; j += 4) {
          unsigned long long u = *(const unsigned long long*)(Wr + j);
          float4 t4 = *(const float4*)(pv + j);
          unsigned lo = (unsigned)u, hi = (unsigned)(u >> 32);
          a += __uint_as_float(lo << 16) * t4.x
             + __uint_as_float(lo & 0xffff0000u) * t4.y
             + __uint_as_float(hi << 16) * t4.z
             + __uint_as_float(hi & 0xffff0000u) * t4.w;
        }
        wp = a;
        Uv[i] = a * Sv[i];
      }
      __syncthreads();
      // matvec2: per-wave partial q_j over this wave's i-range
      for (int j = lane; j < m; j += 64) {
        const unsigned short* Wc = Wl + j;
        float q = 0.f;
        int i = iw0;
        for (; i + 3 < iw1; i += 4)
          q += bf2f(Wc[(i+0)*WPAD]) * Uv[i]   + bf2f(Wc[(i+1)*WPAD]) * Uv[i+1]
             + bf2f(Wc[(i+2)*WPAD]) * Uv[i+2] + bf2f(Wc[(i+3)*WPAD]) * Uv[i+3];
        for (; i < iw1; i++) q += bf2f(Wc[i * WPAD]) * Uv[i];
        pS[wv * MAXM + j] = q;
      }
      __syncthreads();
      // epilogue: wave 0 combines partials, does all CG scalar work in-register
      if (wv == 0) {
        float q0 = 0.f, q1 = 0.f;
        if (j0 < m) q0 = pS[j0] + pS[MAXM + j0] + pS[2*MAXM + j0] + pS[3*MAXM + j0] + 2.f * LAMBDA * p0;
        if (j1 < m) q1 = pS[j1] + pS[MAXM + j1] + pS[2*MAXM + j1] + pS[3*MAXM + j1] + 2.f * LAMBDA * p1;
        float pq = wredF(p0 * q0 + p1 * q1);
        int stop = 0;
        if (!(pq > 0.f)) {
          stop = 1;
          if (lane == 0) cgst[1] = 0;
        } else {
          float alpha = rzf / pq;
          gtpacc += (double)alpha * (double)rzf;
          x0 += alpha * p0; x1 += alpha * p1;
          r0 -= alpha * q0; r1 -= alpha * q1;
          z0 = r0 / dg0;    z1 = r1 / dg1;
          if (lane == 0) { alf_s[0] = alpha; cgst[1] = 1; }
          float rzn = wredF(r0 * z0 + r1 * z1);
          if (rzn < tolf * rz0f || cg == 11) stop = 1;
          else {
            float beta = rzn / rzf;
            p0 = z0 + beta * p0; p1 = z1 + beta * p1;
            pv[j0] = p0; pv[j1] = p1;
            rzf = rzn;
          }
        }
        if (lane == 0) cgst[0] = stop;
      }
      __syncthreads();
    }
    // flush last pending alpha if loop exited without a top-of-loop flush
    if (!brk && cgst[1]) bq += alf_s[0] * wp;
    // publish x and gtp = g^T x = -gtpacc (exact CG identity)
    if (wv == 0) {
      xv[j0] = x0; xv[j1] = x1;
      if (lane == 0) gds[0] = -gtpacc;
    }
    __syncthreads();
    double gtp = gds[0];
    if (!(gtp < 0.0)) break;   // no CG progress => converged/degenerate

    float t = 1.f;
    if (-gtp >= 1e-4) {
      // line search: W.x is already in register bq — no matvec needed
      for (int ls = 0; ls < 10; ls++) {
        double ol = 0.0;
        if (tid < n) ol += (double)(gamma * expf(fminf(av_r + t * bq - 1.f, 30.f)));
        for (int j = tid; j < m; j += 256) {
          float tj = th[j] + t * xv[j];
          ol += (double)(-bc[j] * tj + LAMBDA * tj * tj);
        }
        double ot2 = blockReduceSum(ol, red);
        if (ot2 <= obj + 1e-4 * (double)t * gtp) break;
        t *= 0.5f;
      }
    }
    for (int j = tid; j < mp2; j += 256) th[j] += t * xv[j];
    __syncthreads();
  }

  // ---- final exact f32 evaluation (exp inline, f32 theta), lane-quad coalesced ----
  __syncthreads();
  for (int i = rq; i < n; i += 64) {
    const float* Kr = K + (size_t)i * st + c0;
    float a = 0.f;
#pragma unroll 4
    for (int j = ql; j < m; j += 4) a += th[j] * expf(-Kr[j] * inv_sig);
    a += __shfl_xor(a, 1, 64);
    a += __shfl_xor(a, 2, 64);
    if (ql == 0) Av[i] = a;
  }
  __syncthreads();
  double t1l = 0.0, t2l = 0.0;
  for (int i = tid; i < n; i += 256) t2l += (double)(gamma * expf(fminf(Av[i] - 1.f, 30.f)));
  for (int j = tid; j < m; j += 256) t1l += (double)(bc[j] * th[j]);
  double t1 = blockReduceSum(t1l, red);
  double t2 = blockReduceSum(t2l, red);
  if (tid == 0) {
    atomicAdd(&acc[0], t1);
    atomicAdd(&acc[1], t2);
    __threadfence();
    unsigned old = __hip_atomic_fetch_add(&tick[0], 1u, __ATOMIC_ACQ_REL, __HIP_MEMORY_SCOPE_AGENT);
    if (old == 61u) {
      double a0 = __hip_atomic_load(&acc[0], __ATOMIC_RELAXED, __HIP_MEMORY_SCOPE_AGENT);
      double a1 = __hip_atomic_load(&acc[1], __ATOMIC_RELAXED, __HIP_MEMORY_SCOPE_AGENT);
      out[0] = (float)(a0 - a1);
    }
  }
}

// ---------------- launcher (8 nodes) ----------------
extern "C" void kernel_launch(void* const* d_in, const int* in_sizes, int n_in,
                              void* d_out, int out_size, void* d_ws, size_t ws_size,
                              hipStream_t stream) {
  const float* sf = (const float*)d_in[0];
  const float* tf = (const float*)d_in[1];
  const int* y = (const int*)d_in[2];
  const int* l = (const int*)d_in[3];
  char* ws = (char*)d_ws;

  double*   acc    = (double*)(ws + WS_ACC);
  unsigned* hist0  = (unsigned*)(ws + WS_HIST0);
  unsigned* histA  = (unsigned*)(ws + WS_HISTA);
  unsigned* histB  = (unsigned*)(ws + WS_HISTB);
  unsigned* h2A    = (unsigned*)(ws + WS_H2A);
  unsigned* h2B    = (unsigned*)(ws + WS_H2B);
  unsigned* state  = (unsigned*)(ws + WS_STATE);
  unsigned* tick   = (unsigned*)(ws + WS_TICK);
  int*      meta   = (int*)(ws + WS_META);
  float*    scal   = (float*)(ws + WS_SCAL);
  int*      perm   = (int*)(ws + WS_PERM);
  float*    xnp    = (float*)(ws + WS_XN);
  float*    Ds     = (float*)(ws + WS_DS);
  float*    gK     = (float*)(ws + WS_KBLK);

  hipLaunchKernelGGL(xn_kernel, dim3(1024), dim3(256), 0, stream, sf, tf, xnp, (uint4*)ws, y, l, perm, meta, scal);
  hipLaunchKernelGGL(distbuild_k, dim3(DIST_BLKS + BUILD_TPC * NCLASS), dim3(16, 16), 0, stream,
                     sf, tf, xnp, Ds, hist0, perm, meta, gK);
  hipLaunchKernelGGL(scan0_k, dim3(1), dim3(256), 0, stream, hist0, state);
  hipLaunchKernelGGL(hist1_k, dim3(512), dim3(256), 0, stream, Ds, state, histA, histB);
  hipLaunchKernelGGL(scan1_k, dim3(1), dim3(256), 0, stream, histA, histB, state);
  hipLaunchKernelGGL(hist2_k, dim3(512), dim3(256), 0, stream, Ds, state, h2A, h2B);
  hipLaunchKernelGGL(scan2b_k, dim3(1), dim3(256), 0, stream, h2A, h2B, state, scal);
  hipLaunchKernelGGL(solver_k, dim3(62), dim3(256), 0, stream, gK, meta, scal, acc, tick, (float*)d_out);
}

// Round 15
// 200.088 us; speedup vs baseline: 1.0344x; 1.0334x over previous
//
#include <hip/hip_runtime.h>
#include <math.h>

#define N_TOT   4096
#define N_SRC   2048
#define DIMF    256
#define NCLASS  31
#define LAMBDA  0.01f

// median target ranks among the 2,096,128 strict-lower-triangle values.
#define K_TRI1  1048063LL
#define K_TRI2  1048064LL

// ---- ws layout (bytes) ----
#define WS_ACC    0           // 2 doubles
#define WS_HIST0  64          // 4096 u32
#define WS_HISTA  16448       // 4096 u32
#define WS_HISTB  32832       // 4096 u32
#define WS_H2A    49216       // 256 u32
#define WS_H2B    50240       // 256 u32
#define WS_STATE  51264       // 64 u32 (st[0..7])
#define WS_TICK   51520       // 4 u32 (solver final ticket)
#define WS_META   52288       // 128 i32: ncls[32], m0c[32], cstart[32], blkoff[32]
#define WS_SCAL   52800       // 16 f32: [0]=sigma, [1]=gamma0, [2]=gamma1
#define ZERO_BYTES 53248
#define WS_PERM   53248       // 4096 i32
#define WS_XN     69632       // 4096 f32
#define WS_DS     1048576     // 2048*2048 f32 (lower triangle used)
#define WS_KBLK   17825792    // class K blocks (8 MB); holds RAW d (read-only in solver)

#define MAXW 224
#define MAXM 112
#define WPAD 116   // u16 row stride = 58 dwords: rows 8B-aligned (b64 reads);
                   // column reads: 64 lanes x 2B = 128B = 32 banks, 2 lanes/bank (free, m136)

#define DIST_BLKS 528
#define BUILD_TPC 105   // tiles per class: T<=14 -> T(T+1)/2 <= 105

__device__ __forceinline__ float bf2f(unsigned short h) {
  return __uint_as_float(((unsigned)h) << 16);
}

// f32 butterfly reduce across one wave (all lanes get the sum)
__device__ __forceinline__ float wredF(float v) {
#pragma unroll
  for (int o = 1; o < 64; o <<= 1) v += __shfl_xor(v, o, 64);
  return v;
}

// ---------------- reductions (256 threads) ----------------
__device__ __forceinline__ double blockReduceSum(double v, double* red) {
#pragma unroll
  for (int o = 32; o > 0; o >>= 1) v += __shfl_down(v, o, 64);
  int w = threadIdx.x >> 6, lane = threadIdx.x & 63;
  __syncthreads();
  if (lane == 0) red[w] = v;
  __syncthreads();
  return red[0] + red[1] + red[2] + red[3];
}

__device__ __forceinline__ void blockReduceSumMax(double s, double mx, double* red,
                                                  double& os, double& om) {
#pragma unroll
  for (int o = 32; o > 0; o >>= 1) {
    s += __shfl_down(s, o, 64);
    double u = __shfl_down(mx, o, 64);
    mx = fmax(mx, u);
  }
  int w = threadIdx.x >> 6, lane = threadIdx.x & 63;
  __syncthreads();
  if (lane == 0) { red[w] = s; red[4 + w] = mx; }
  __syncthreads();
  os = red[0] + red[1] + red[2] + red[3];
  om = fmax(fmax(red[4], red[5]), fmax(red[6], red[7]));
}

// scan over histogram (256 threads) — parallel Hillis-Steele prefix scan (measured-best)
__device__ void scan_find(const unsigned* hist, int nbins, long long k, unsigned* shOut, int tid) {
  __shared__ long long tsum[256];
  int per = nbins / 256;
  long long s = 0;
  for (int q = 0; q < per; q++) s += hist[tid * per + q];
  tsum[tid] = s;
  __syncthreads();
  long long acc = s;
  for (int off = 1; off < 256; off <<= 1) {
    long long add = (tid >= off) ? tsum[tid - off] : 0;
    __syncthreads();
    acc += add;
    tsum[tid] = acc;
    __syncthreads();
  }
  long long run = acc - s;   // exclusive prefix for this thread's bin range
  for (int q = 0; q < per; q++) {
    unsigned c = hist[tid * per + q];
    if (k >= run && k < run + (long long)c) { shOut[0] = (unsigned)(tid * per + q); shOut[1] = (unsigned)(k - run); }
    run += c;
  }
  __syncthreads();
}

// ---- row norms + ws zeroing + class/domain bucketing (block 0; y,l available at t=0) ----
__global__ __launch_bounds__(256) void xn_kernel(const float* __restrict__ sf,
                                                 const float* __restrict__ tf,
                                                 float* __restrict__ xn,
                                                 uint4* __restrict__ wsz,
                                                 const int* __restrict__ y,
                                                 const int* __restrict__ l,
                                                 int* __restrict__ perm,
                                                 int* __restrict__ meta,
                                                 float* __restrict__ scal) {
  __shared__ unsigned cl[64];
  __shared__ unsigned bs2[64];
  __shared__ unsigned cur[64];
  const int tid = threadIdx.x;
  if (blockIdx.x == 0) {
    uint4 z; z.x = 0; z.y = 0; z.z = 0; z.w = 0;
    for (int q = tid; q < ZERO_BYTES / 16; q += 256) wsz[q] = z;
    if (tid < 64) cl[tid] = 0;
    __syncthreads();
    for (int i = tid; i < N_TOT; i += 256) atomicAdd(&cl[y[i] * 2 + l[i]], 1u);
    __syncthreads();
    if (tid == 0) {
      unsigned run = 0;
      for (int b2 = 0; b2 < 62; b2++) { bs2[b2] = run; run += cl[b2]; }
      unsigned run2 = 0, cnt0 = 0;
      for (int c = 0; c < NCLASS; c++) {
        int n = (int)(cl[2 * c] + cl[2 * c + 1]);
        meta[c] = n; meta[32 + c] = (int)cl[2 * c]; meta[64 + c] = (int)bs2[2 * c];
        meta[96 + c] = (int)run2; run2 += (unsigned)(n * n);
        cnt0 += cl[2 * c];
      }
      scal[1] = (float)((double)cnt0 / (4096.0 * 4096.0));
      scal[2] = (float)((double)(N_TOT - cnt0) / (4096.0 * 4096.0));
    }
    __syncthreads();
    if (tid < 64) cur[tid] = bs2[tid];
    __syncthreads();
    for (int i = tid; i < N_TOT; i += 256) {
      int b2 = y[i] * 2 + l[i];
      unsigned pos = atomicAdd(&cur[b2], 1u);
      perm[pos] = i;
    }
  }
  int wid = tid >> 6, lane = tid & 63;
  int row = blockIdx.x * 4 + wid;
  const float* src = (row < N_SRC) ? (sf + (size_t)row * DIMF) : (tf + (size_t)(row - N_SRC) * DIMF);
  float4 v = ((const float4*)src)[lane];
  float s = v.x * v.x + v.y * v.y + v.z * v.z + v.w * v.w;
#pragma unroll
  for (int o = 32; o > 0; o >>= 1) s += __shfl_down(s, o, 64);
  if (lane == 0) xn[row] = s;
}

// ------- MERGED: blocks [0,528) = source pairwise sq-dists + fused hist0 (unchanged);
//         blocks [528, 528+105*31) = per-class K-block RAW distances (no sigma dep!)
//         build-d depends only on xn/perm/meta (ready after xn_kernel) -> runs ~15us
//         of former build_k work overlapped with dist instead of after scan2b.
//         LDS union'd (41472 B both branches) -> occupancy unchanged. -------
__global__ __launch_bounds__(256) void distbuild_k(const float* __restrict__ sf,
                                                   const float* __restrict__ tf,
                                                   const float* __restrict__ xn,
                                                   float* __restrict__ Ds,
                                                   unsigned* __restrict__ h,
                                                   const int* __restrict__ perm,
                                                   const int* __restrict__ meta,
                                                   float* __restrict__ gK) {
  __shared__ __align__(16) char smem[41472];
  const int tx = threadIdx.x, ty = threadIdx.y;
  const int tid = ty * 16 + tx;

  if (blockIdx.x < DIST_BLKS) {
    // ================= dist branch (byte-identical logic to measured-best) =================
    float (*As)[68] = (float(*)[68])smem;                      // 4352 B
    float (*Bs)[68] = (float(*)[68])(smem + 4352);             // 4352 B
    unsigned (*lh)[4096] = (unsigned(*)[4096])(smem + 8704);   // 32768 B
    const int par = tid & 1;
    for (int q = tid; q < 8192; q += 256) lh[q >> 12][q & 4095] = 0;
    int b = blockIdx.x;
    int by = (int)((sqrtf(8.f * (float)b + 1.f) - 1.f) * 0.5f);
    while ((by + 1) * (by + 2) / 2 <= b) ++by;
    while (by * (by + 1) / 2 > b) --by;
    int bx = b - by * (by + 1) / 2;
    const int R = by * 64, C = bx * 64;
    const int si = tid >> 2, sq = tid & 3;
    float4 va = ((const float4*)(sf + (size_t)(R + si) * 256 + 0))[sq];
    float4 vb = ((const float4*)(sf + (size_t)(C + si) * 256 + 0))[sq];
    float acc[4][4] = {};
    for (int kc = 0; kc < 256; kc += 16) {
      As[sq * 4 + 0][si] = va.x; As[sq * 4 + 1][si] = va.y; As[sq * 4 + 2][si] = va.z; As[sq * 4 + 3][si] = va.w;
      Bs[sq * 4 + 0][si] = vb.x; Bs[sq * 4 + 1][si] = vb.y; Bs[sq * 4 + 2][si] = vb.z; Bs[sq * 4 + 3][si] = vb.w;
      __syncthreads();
      if (kc + 16 < 256) {
        va = ((const float4*)(sf + (size_t)(R + si) * 256 + kc + 16))[sq];
        vb = ((const float4*)(sf + (size_t)(C + si) * 256 + kc + 16))[sq];
      }
#pragma unroll
      for (int k = 0; k < 16; k++) {
        float4 a = *(const float4*)&As[k][ty * 4];
        float4 b2 = *(const float4*)&Bs[k][tx * 4];
        acc[0][0] += a.x * b2.x; acc[0][1] += a.x * b2.y; acc[0][2] += a.x * b2.z; acc[0][3] += a.x * b2.w;
        acc[1][0] += a.y * b2.x; acc[1][1] += a.y * b2.y; acc[1][2] += a.y * b2.z; acc[1][3] += a.y * b2.w;
        acc[2][0] += a.z * b2.x; acc[2][1] += a.z * b2.y; acc[2][2] += a.z * b2.z; acc[2][3] += a.z * b2.w;
        acc[3][0] += a.w * b2.x; acc[3][1] += a.w * b2.y; acc[3][2] += a.w * b2.z; acc[3][3] += a.w * b2.w;
      }
      __syncthreads();
    }
    int jbase = C + tx * 4;
    float xnj0 = xn[jbase + 0], xnj1 = xn[jbase + 1], xnj2 = xn[jbase + 2], xnj3 = xn[jbase + 3];
#pragma unroll
    for (int r = 0; r < 4; r++) {
      int i = R + ty * 4 + r;
      float xni = xn[i];
      float v[4];
      v[0] = fmaxf(xni + xnj0 - 2.f * acc[r][0], 0.f);
      v[1] = fmaxf(xni + xnj1 - 2.f * acc[r][1], 0.f);
      v[2] = fmaxf(xni + xnj2 - 2.f * acc[r][2], 0.f);
      v[3] = fmaxf(xni + xnj3 - 2.f * acc[r][3], 0.f);
      if (jbase + 3 < i) {
        float4 o; o.x = v[0]; o.y = v[1]; o.z = v[2]; o.w = v[3];
        ((float4*)&Ds[(size_t)i * 2048 + jbase])[0] = o;
        atomicAdd(&lh[par][__float_as_uint(v[0]) >> 20], 1u);
        atomicAdd(&lh[par][__float_as_uint(v[1]) >> 20], 1u);
        atomicAdd(&lh[par][__float_as_uint(v[2]) >> 20], 1u);
        atomicAdd(&lh[par][__float_as_uint(v[3]) >> 20], 1u);
      } else {
#pragma unroll
        for (int k = 0; k < 4; k++) {
          if (jbase + k < i) {
            Ds[(size_t)i * 2048 + jbase + k] = v[k];
            atomicAdd(&lh[par][__float_as_uint(v[k]) >> 20], 1u);
          }
        }
      }
    }
    __syncthreads();
    for (int q = tid; q < 4096; q += 256) {
      unsigned v = lh[0][q] + lh[1][q];
      if (v) atomicAdd(&h[q], v);
    }
  } else {
    // ================= build-d branch (former build_k, storing RAW d) =================
    float (*As)[260] = (float(*)[260])smem;                    // 16640 B
    float (*Bs)[260] = (float(*)[260])(smem + 16640);          // 16640 B
    float (*ot)[17]  = (float(*)[17])(smem + 33280);           // 1088 B
    int* ra = (int*)(smem + 34368);                            // 64 B
    int* rb = (int*)(smem + 34432);                            // 64 B
    int b2 = blockIdx.x - DIST_BLKS;
    const int c = b2 / BUILD_TPC;
    int b = b2 - c * BUILD_TPC;
    const int n = meta[c];
    const int cs = meta[64 + c];
    const int bo = meta[96 + c];
    const int T = (n + 15) >> 4;
    if (b >= T * (T + 1) / 2) return;
    int by = (int)((sqrtf(8.f * (float)b + 1.f) - 1.f) * 0.5f);
    while ((by + 1) * (by + 2) / 2 <= b) ++by;
    while (by * (by + 1) / 2 > b) --by;
    int bx = b - by * (by + 1) / 2;
    const int i0 = by * 16, j0 = bx * 16;
    if (tid < 16) { int il = i0 + tid; ra[tid] = (il < n) ? perm[cs + il] : -1; }
    else if (tid < 32) { int jl = j0 + tid - 16; rb[tid - 16] = (jl < n) ? perm[cs + jl] : -1; }
    __syncthreads();
    for (int e = tid; e < 1024; e += 256) {
      int r = e >> 6, q = e & 63;
      int g = ra[r];
      if (g >= 0) {
        const float* src = (g < N_SRC) ? (sf + (size_t)g * DIMF) : (tf + (size_t)(g - N_SRC) * DIMF);
        ((float4*)&As[r][q * 4])[0] = ((const float4*)src)[q];
      }
      int g2 = rb[r];
      if (g2 >= 0) {
        const float* src = (g2 < N_SRC) ? (sf + (size_t)g2 * DIMF) : (tf + (size_t)(g2 - N_SRC) * DIMF);
        ((float4*)&Bs[r][q * 4])[0] = ((const float4*)src)[q];
      }
    }
    __syncthreads();
    int il = i0 + ty, jl = j0 + tx;
    float val = 0.f;
    if (il < n && jl < n) {
      float dot = 0.f;
      const float4* a4 = (const float4*)&As[ty][0];
      const float4* b4 = (const float4*)&Bs[tx][0];
#pragma unroll 16
      for (int q = 0; q < 64; q++) {
        float4 a = a4[q], bb = b4[q];
        dot += a.x * bb.x + a.y * bb.y + a.z * bb.z + a.w * bb.w;
      }
      int gi = ra[ty], gj = rb[tx];
      val = xn[gi] + xn[gj] - 2.f * dot;   // RAW d (exp applied in solver with sigma)
      gK[(size_t)bo + (size_t)il * n + jl] = val;
    }
    ot[ty][tx] = val;
    __syncthreads();
    if (by != bx) {
      int il2 = j0 + ty, jl2 = i0 + tx;
      if (il2 < n && jl2 < n) gK[(size_t)bo + (size_t)il2 * n + jl2] = ot[tx][ty];
    }
  }
}

__global__ __launch_bounds__(256) void scan0_k(const unsigned* __restrict__ h, unsigned* __restrict__ st) {
  __shared__ unsigned r0[2];
  __shared__ unsigned r1[2];
  scan_find(h, 4096, K_TRI1, r0, threadIdx.x);
  scan_find(h, 4096, K_TRI2, r1, threadIdx.x);
  if (threadIdx.x == 0) { st[0] = r0[0]; st[1] = r0[1]; st[2] = r1[0]; st[3] = r1[1]; }
}

// ---------------- radix pass 1 (triangle reads, sequential rows) ----------------
__global__ __launch_bounds__(256) void hist1_k(const float* __restrict__ Ds, const unsigned* __restrict__ st,
                                               unsigned* __restrict__ hA, unsigned* __restrict__ hB) {
  __shared__ unsigned lA[4096];
  __shared__ unsigned lB[4096];
  for (int i = threadIdx.x; i < 4096; i += 256) { lA[i] = 0; lB[i] = 0; }
  __syncthreads();
  unsigned s0 = st[0], s1 = st[2];
  int gw = (blockIdx.x * 256 + threadIdx.x) >> 6;
  int lane = threadIdx.x & 63;
  const float* row = Ds + (size_t)gw * 2048;
  for (int j = lane; j < gw; j += 64) {
    unsigned u = __float_as_uint(row[j]);
    unsigned hi = u >> 20, mid = (u >> 8) & 0xFFFu;
    if (hi == s0) atomicAdd(&lA[mid], 1u);
    if (hi == s1) atomicAdd(&lB[mid], 1u);
  }
  __syncthreads();
  for (int i = threadIdx.x; i < 4096; i += 256) {
    if (lA[i]) atomicAdd(&hA[i], lA[i]);
    if (lB[i]) atomicAdd(&hB[i], lB[i]);
  }
}

__global__ __launch_bounds__(256) void scan1_k(const unsigned* __restrict__ hA, const unsigned* __restrict__ hB,
                                               unsigned* __restrict__ st) {
  __shared__ unsigned r0[2];
  __shared__ unsigned r1[2];
  long long kA = (long long)st[1];
  long long kB = (long long)st[3];
  scan_find(hA, 4096, kA, r0, threadIdx.x);
  scan_find(hB, 4096, kB, r1, threadIdx.x);
  if (threadIdx.x == 0) { st[4] = r0[0]; st[5] = r0[1]; st[6] = r1[0]; st[7] = r1[1]; }
}

// ---------------- radix pass 2 (triangle reads, sequential rows) ----------------
__global__ __launch_bounds__(256) void hist2_k(const float* __restrict__ Ds, const unsigned* __restrict__ st,
                                               unsigned* __restrict__ hA, unsigned* __restrict__ hB) {
  __shared__ unsigned lA[256];
  __shared__ unsigned lB[256];
  lA[threadIdx.x] = 0; lB[threadIdx.x] = 0;
  __syncthreads();
  unsigned p0 = (st[0] << 12) | st[4];
  unsigned p1 = (st[2] << 12) | st[6];
  int gw = (blockIdx.x * 256 + threadIdx.x) >> 6;
  int lane = threadIdx.x & 63;
  const float* row = Ds + (size_t)gw * 2048;
  for (int j = lane; j < gw; j += 64) {
    unsigned u = __float_as_uint(row[j]);
    unsigned pre = u >> 8;
    if (pre == p0) atomicAdd(&lA[u & 0xFFu], 1u);
    if (pre == p1) atomicAdd(&lB[u & 0xFFu], 1u);
  }
  __syncthreads();
  if (lA[threadIdx.x]) atomicAdd(&hA[threadIdx.x], lA[threadIdx.x]);
  if (lB[threadIdx.x]) atomicAdd(&hB[threadIdx.x], lB[threadIdx.x]);
}

// ------- scan2: sigma only (bucketing lives in xn_kernel block 0) -------
__global__ __launch_bounds__(256) void scan2b_k(const unsigned* __restrict__ hA, const unsigned* __restrict__ hB,
                                                const unsigned* __restrict__ st, float* __restrict__ scal) {
  int tid = threadIdx.x;
  __shared__ unsigned r0[2];
  __shared__ unsigned r1[2];
  scan_find(hA, 256, (long long)st[5], r0, tid);
  scan_find(hB, 256, (long long)st[7], r1, tid);
  if (tid == 0) {
    unsigned v1 = (st[0] << 20) | (st[4] << 8) | r0[0];
    unsigned v2 = (st[2] << 20) | (st[6] << 8) | r1[0];
    scal[0] = 0.5f * (__uint_as_float(v1) + __uint_as_float(v2));  // sigma
  }
}

// ---------------- per-(class,domain) Newton-PCG + fused final (256 threads) ----------------
// R12 measured-best (200.2): gK holds RAW d; solver applies K=expf(-d*inv_sig)
// inline at W-staging, bc, and final-eval. Separate bc pass (R14's staging fusion
// regressed +6.4us); no gK write-back (R13's regressed +8us).
__global__ __launch_bounds__(256) void solver_k(const float* __restrict__ gK, const int* __restrict__ meta,
                                                const float* __restrict__ scal, double* __restrict__ acc,
                                                unsigned* __restrict__ tick, float* __restrict__ out) {
  const int c = blockIdx.x >> 1, d = blockIdx.x & 1;
  const int n = meta[c];
  const int m0 = meta[32 + c];
  const int m = d ? (n - m0) : m0;
  const int c0 = d ? m0 : 0;
  const int bo = meta[96 + c];
  const float gamma = scal[1 + d];
  const float inv_sig = 1.f / scal[0];
  const int tid = threadIdx.x;
  const int wv = tid >> 6, lane = tid & 63;

  __shared__ unsigned short Wl[MAXW * WPAD];   // 51968 B
  __shared__ float pS[4 * MAXM];
  __shared__ float pD[4 * MAXM];
  __shared__ float Av[MAXW];
  __shared__ float Sv[MAXW];
  __shared__ float Uv[MAXW];
  __shared__ float bc[MAXM];
  __shared__ float gv[MAXM];
  __shared__ float dgv[MAXM];
  __shared__ alignas(16) float th[128];
  __shared__ alignas(16) float pv[128];
  __shared__ alignas(16) float xv[128];
  __shared__ double red[16];
  __shared__ double gds[2];
  __shared__ float alf_s[2];
  __shared__ int cgst[2];

  const float* K = gK + bo;
  const int st = n;
  const int mp2 = (m + 1) & ~1;
  const int mp4 = (m + 3) & ~3;
  const int iw0 = (n * wv) >> 2, iw1 = (n * (wv + 1)) >> 2;
  const int rq = tid >> 2, ql = tid & 3;

  for (int i = rq; i < n; i += 64) {
    const float* Kr = K + (size_t)i * st + c0;
    unsigned short* Wr = Wl + i * WPAD;
    for (int j = ql; j < m; j += 4) {
      float e = expf(-Kr[j] * inv_sig);
      unsigned u = __float_as_uint(e);
      u += 0x7fffu + ((u >> 16) & 1u);   // RNE to bf16
      Wr[j] = (unsigned short)(u >> 16);
    }
    if (ql == 0) for (int j = m; j < mp4; j++) Wr[j] = 0;
  }
  // bc: column means, lane-quad coalesced (quad reads 4 consecutive floats), exp inline
  for (int j = rq; j < m; j += 64) {
    const float* Kr = K + (size_t)(c0 + j) * st + c0;
    float s = 0.f;
    for (int r = ql; r < m; r += 4) s += expf(-Kr[r] * inv_sig);
    s += __shfl_xor(s, 1, 64);
    s += __shfl_xor(s, 2, 64);
    if (ql == 0) bc[j] = s * (1.0f / 4096.0f);
  }
  __syncthreads();
  for (int j = tid; j < 128; j += 256) { th[j] = 0.f; pv[j] = 0.f; xv[j] = 0.f; }
  __syncthreads();

  float av_r = 0.f;   // this thread's Av[tid] (n <= 224 < 256: one row per thread)

  for (int it = 0; it < 25; it++) {
    double o = 0.0;
    if (it == 0) {
      const float s0c = gamma * expf(-1.f);
      av_r = 0.f;
      for (int i = tid; i < n; i += 256) { Sv[i] = s0c; o += (double)s0c; }
    } else {
      // merged: Av matvec -> S -> obj contribution (b64 W reads, broadcast th)
      for (int i = tid; i < n; i += 256) {
        const unsigned short* Wr = Wl + i * WPAD;
        float a = 0.f;
#pragma unroll 4
        for (int j = 0; j < mp4; j += 4) {
          unsigned long long u = *(const unsigned long long*)(Wr + j);
          float4 t4 = *(const float4*)(th + j);
          unsigned lo = (unsigned)u, hi = (unsigned)(u >> 32);
          a += __uint_as_float(lo << 16) * t4.x
             + __uint_as_float(lo & 0xffff0000u) * t4.y
             + __uint_as_float(hi << 16) * t4.z
             + __uint_as_float(hi & 0xffff0000u) * t4.w;
        }
        av_r = a;
        float si = gamma * expf(fminf(a - 1.f, 30.f));
        Sv[i] = si; o += (double)si;
      }
      for (int j = tid; j < m; j += 256) {
        float t_ = th[j];
        o += (double)(-bc[j] * t_ + LAMBDA * t_ * t_);
      }
    }
    __syncthreads();
    // ---- gradient (+ Jacobi diag at it==0 only; frozen after) ----
    if (it == 0) {
      for (int j = lane; j < m; j += 64) {
        const unsigned short* Wc = Wl + j;
        float s_ = 0.f, ds_ = 0.f;
        int i = iw0;
        for (; i + 3 < iw1; i += 4) {
          float w0 = bf2f(Wc[(i + 0) * WPAD]), w1 = bf2f(Wc[(i + 1) * WPAD]);
          float w2 = bf2f(Wc[(i + 2) * WPAD]), w3 = bf2f(Wc[(i + 3) * WPAD]);
          float a0 = w0 * Sv[i], a1 = w1 * Sv[i + 1], a2 = w2 * Sv[i + 2], a3 = w3 * Sv[i + 3];
          s_ += a0 + a1 + a2 + a3;
          ds_ += a0 * w0 + a1 * w1 + a2 * w2 + a3 * w3;
        }
        for (; i < iw1; i++) { float w = bf2f(Wc[i * WPAD]); float a = w * Sv[i]; s_ += a; ds_ += a * w; }
        pS[wv * MAXM + j] = s_; pD[wv * MAXM + j] = ds_;
      }
    } else {
      for (int j = lane; j < m; j += 64) {
        const unsigned short* Wc = Wl + j;
        float s_ = 0.f;
        int i = iw0;
        for (; i + 3 < iw1; i += 4)
          s_ += bf2f(Wc[(i+0)*WPAD]) * Sv[i]   + bf2f(Wc[(i+1)*WPAD]) * Sv[i+1]
              + bf2f(Wc[(i+2)*WPAD]) * Sv[i+2] + bf2f(Wc[(i+3)*WPAD]) * Sv[i+3];
        for (; i < iw1; i++) s_ += bf2f(Wc[i * WPAD]) * Sv[i];
        pS[wv * MAXM + j] = s_;
      }
    }
    __syncthreads();
    double gm = 0.0;
    for (int j = tid; j < m; j += 256) {
      float s_ = pS[j] + pS[MAXM + j] + pS[2 * MAXM + j] + pS[3 * MAXM + j];
      if (it == 0) {
        float ds_ = pD[j] + pD[MAXM + j] + pD[2 * MAXM + j] + pD[3 * MAXM + j];
        dgv[j] = ds_ + 2.f * LAMBDA;
      }
      float g = s_ - bc[j] + 2.f * LAMBDA * th[j];
      gv[j] = g;
      double ag = fabs((double)g); if (ag > gm) gm = ag;
    }
    double obj, gmax;
    blockReduceSumMax(o, gm, red, obj, gmax);
    if (gmax < 1e-5) break;

    // ---- PCG solve H x = -g: state register-resident in wave 0 ----
    const float tolf = (it == 0) ? 1e-2f : ((it == 1) ? 1e-3f : 1e-4f);
    float p0 = 0.f, p1 = 0.f, r0 = 0.f, r1 = 0.f, z0 = 0.f, z1 = 0.f, x0 = 0.f, x1 = 0.f;
    float dg0 = 1.f, dg1 = 1.f, rzf = 0.f, rz0f = 0.f;
    float bq = 0.f, wp = 0.f;   // bq = (W x)[tid] accumulated; wp = (W p)[tid]
    double gtpacc = 0.0;   // block-uniform in wave0: sum of alpha_k * rz_k = -g^T x
    const int j0 = lane, j1 = lane + 64;
    if (wv == 0) {
      if (j0 < m) { dg0 = dgv[j0]; r0 = -gv[j0]; z0 = r0 / dg0; }
      if (j1 < m) { dg1 = dgv[j1]; r1 = -gv[j1]; z1 = r1 / dg1; }
      p0 = z0; p1 = z1;
      rzf = wredF(r0 * z0 + r1 * z1);
      rz0f = rzf;
      pv[j0] = p0; pv[j1] = p1;
      if (lane == 0) { cgst[0] = (rzf > 0.f) ? 0 : 1; cgst[1] = 0; }
    }
    __syncthreads();
    bool brk = false;
    for (int cg = 0; cg < 12; cg++) {
      // flush pending alpha from previous CG iter (wp still holds prev W.p)
      if (cgst[1]) bq += alf_s[0] * wp;
      if (cgst[0]) { brk = true; break; }
      // matvec1: Uv = Sv .* (W pv)  (one row per thread)
      for (int i = tid; i < n; i += 256) {
        const unsigned short* Wr = Wl + i * WPAD;
        float a = 0.f;
#pragma unroll 4
        for (int j = 0; j < mp4; j += 4) {
          unsigned long long u = *(const unsigned long long*)(Wr + j);
          float4 t4 = *(const float4*)(pv + j);
          unsigned lo = (unsigned)u, hi = (unsigned)(u >> 32);
          a += __uint_as_float(lo << 16) * t4.x
             + __uint_as_float(lo & 0xffff0000u) * t4.y
             + __uint_as_float(hi << 16) * t4.z
             + __uint_as_float(hi & 0xffff0000u) * t4.w;
        }
        wp = a;
        Uv[i] = a * Sv[i];
      }
      __syncthreads();
      // matvec2: per-wave partial q_j over this wave's i-range
      for (int j = lane; j < m; j += 64) {
        const unsigned short* Wc = Wl + j;
        float q = 0.f;
        int i = iw0;
        for (; i + 3 < iw1; i += 4)
          q += bf2f(Wc[(i+0)*WPAD]) * Uv[i]   + bf2f(Wc[(i+1)*WPAD]) * Uv[i+1]
             + bf2f(Wc[(i+2)*WPAD]) * Uv[i+2] + bf2f(Wc[(i+3)*WPAD]) * Uv[i+3];
        for (; i < iw1; i++) q += bf2f(Wc[i * WPAD]) * Uv[i];
        pS[wv * MAXM + j] = q;
      }
      __syncthreads();
      // epilogue: wave 0 combines partials, does all CG scalar work in-register
      if (wv == 0) {
        float q0 = 0.f, q1 = 0.f;
        if (j0 < m) q0 = pS[j0] + pS[MAXM + j0] + pS[2*MAXM + j0] + pS[3*MAXM + j0] + 2.f * LAMBDA * p0;
        if (j1 < m) q1 = pS[j1] + pS[MAXM + j1] + pS[2*MAXM + j1] + pS[3*MAXM + j1] + 2.f * LAMBDA * p1;
        float pq = wredF(p0 * q0 + p1 * q1);
        int stop = 0;
        if (!(pq > 0.f)) {
          stop = 1;
          if (lane == 0) cgst[1] = 0;
        } else {
          float alpha = rzf / pq;
          gtpacc += (double)alpha * (double)rzf;
          x0 += alpha * p0; x1 += alpha * p1;
          r0 -= alpha * q0; r1 -= alpha * q1;
          z0 = r0 / dg0;    z1 = r1 / dg1;
          if (lane == 0) { alf_s[0] = alpha; cgst[1] = 1; }
          float rzn = wredF(r0 * z0 + r1 * z1);
          if (rzn < tolf * rz0f || cg == 11) stop = 1;
          else {
            float beta = rzn / rzf;
            p0 = z0 + beta * p0; p1 = z1 + beta * p1;
            pv[j0] = p0; pv[j1] = p1;
            rzf = rzn;
          }
        }
        if (lane == 0) cgst[0] = stop;
      }
      __syncthreads();
    }
    // flush last pending alpha if loop exited without a top-of-loop flush
    if (!brk && cgst[1]) bq += alf_s[0] * wp;
    // publish x and gtp = g^T x = -gtpacc (exact CG identity)
    if (wv == 0) {
      xv[j0] = x0; xv[j1] = x1;
      if (lane == 0) gds[0] = -gtpacc;
    }
    __syncthreads();
    double gtp = gds[0];
    if (!(gtp < 0.0)) break;   // no CG progress => converged/degenerate

    float t = 1.f;
    if (-gtp >= 1e-4) {
      // line search: W.x is already in register bq — no matvec needed
      for (int ls = 0; ls < 10; ls++) {
        double ol = 0.0;
        if (tid < n) ol += (double)(gamma * expf(fminf(av_r + t * bq - 1.f, 30.f)));
        for (int j = tid; j < m; j += 256) {
          float tj = th[j] + t * xv[j];
          ol += (double)(-bc[j] * tj + LAMBDA * tj * tj);
        }
        double ot2 = blockReduceSum(ol, red);
        if (ot2 <= obj + 1e-4 * (double)t * gtp) break;
        t *= 0.5f;
      }
    }
    for (int j = tid; j < mp2; j += 256) th[j] += t * xv[j];
    __syncthreads();
  }

  // ---- final exact f32 evaluation (exp inline, f32 theta), lane-quad coalesced ----
  __syncthreads();
  for (int i = rq; i < n; i += 64) {
    const float* Kr = K + (size_t)i * st + c0;
    float a = 0.f;
#pragma unroll 4
    for (int j = ql; j < m; j += 4) a += th[j] * expf(-Kr[j] * inv_sig);
    a += __shfl_xor(a, 1, 64);
    a += __shfl_xor(a, 2, 64);
    if (ql == 0) Av[i] = a;
  }
  __syncthreads();
  double t1l = 0.0, t2l = 0.0;
  for (int i = tid; i < n; i += 256) t2l += (double)(gamma * expf(fminf(Av[i] - 1.f, 30.f)));
  for (int j = tid; j < m; j += 256) t1l += (double)(bc[j] * th[j]);
  double t1 = blockReduceSum(t1l, red);
  double t2 = blockReduceSum(t2l, red);
  if (tid == 0) {
    atomicAdd(&acc[0], t1);
    atomicAdd(&acc[1], t2);
    __threadfence();
    unsigned old = __hip_atomic_fetch_add(&tick[0], 1u, __ATOMIC_ACQ_REL, __HIP_MEMORY_SCOPE_AGENT);
    if (old == 61u) {
      double a0 = __hip_atomic_load(&acc[0], __ATOMIC_RELAXED, __HIP_MEMORY_SCOPE_AGENT);
      double a1 = __hip_atomic_load(&acc[1], __ATOMIC_RELAXED, __HIP_MEMORY_SCOPE_AGENT);
      out[0] = (float)(a0 - a1);
    }
  }
}

// ---------------- launcher (8 nodes; build-d packed into dist, exp inline in solver) ----------------
extern "C" void kernel_launch(void* const* d_in, const int* in_sizes, int n_in,
                              void* d_out, int out_size, void* d_ws, size_t ws_size,
                              hipStream_t stream) {
  const float* sf = (const float*)d_in[0];
  const float* tf = (const float*)d_in[1];
  const int* y = (const int*)d_in[2];
  const int* l = (const int*)d_in[3];
  char* ws = (char*)d_ws;

  double*   acc    = (double*)(ws + WS_ACC);
  unsigned* hist0  = (unsigned*)(ws + WS_HIST0);
  unsigned* histA  = (unsigned*)(ws + WS_HISTA);
  unsigned* histB  = (unsigned*)(ws + WS_HISTB);
  unsigned* h2A    = (unsigned*)(ws + WS_H2A);
  unsigned* h2B    = (unsigned*)(ws + WS_H2B);
  unsigned* state  = (unsigned*)(ws + WS_STATE);
  unsigned* tick   = (unsigned*)(ws + WS_TICK);
  int*      meta   = (int*)(ws + WS_META);
  float*    scal   = (float*)(ws + WS_SCAL);
  int*      perm   = (int*)(ws + WS_PERM);
  float*    xnp    = (float*)(ws + WS_XN);
  float*    Ds     = (float*)(ws + WS_DS);
  float*    gK     = (float*)(ws + WS_KBLK);

  hipLaunchKernelGGL(xn_kernel, dim3(1024), dim3(256), 0, stream, sf, tf, xnp, (uint4*)ws, y, l, perm, meta, scal);
  hipLaunchKernelGGL(distbuild_k, dim3(DIST_BLKS + BUILD_TPC * NCLASS), dim3(16, 16), 0, stream,
                     sf, tf, xnp, Ds, hist0, perm, meta, gK);
  hipLaunchKernelGGL(scan0_k, dim3(1), dim3(256), 0, stream, hist0, state);
  hipLaunchKernelGGL(hist1_k, dim3(512), dim3(256), 0, stream, Ds, state, histA, histB);
  hipLaunchKernelGGL(scan1_k, dim3(1), dim3(256), 0, stream, histA, histB, state);
  hipLaunchKernelGGL(hist2_k, dim3(512), dim3(256), 0, stream, Ds, state, h2A, h2B);
  hipLaunchKernelGGL(scan2b_k, dim3(1), dim3(256), 0, stream, h2A, h2B, state, scal);
  hipLaunchKernelGGL(solver_k, dim3(62), dim3(256), 0, stream, gK, meta, scal, acc, tick, (float*)d_out);
}